// Round 12
// baseline (515.547 us; speedup 1.0000x reference)
//
#include <hip/hip_runtime.h>

// ---------------- problem constants ----------------
#define B_    2
#define S_    2048
#define HID_  3584
#define H_    16
#define KV_   8
#define D_    256
#define RQ_   6
#define NPROJ 2688
#define HD_   4096
#define MTOK  4096
#define EPS_  1e-6f
#define NEG_  -2.3819763e38f
#define SCALE_ 0.0625f   // 256^-0.5

typedef unsigned short u16;
typedef __attribute__((ext_vector_type(8))) short short8;
typedef __attribute__((ext_vector_type(4))) float f32x4;

__device__ __forceinline__ u16 f2bf(float f) {
  unsigned u = __float_as_uint(f);
  u += 0x7fffu + ((u >> 16) & 1u);
  return (u16)(u >> 16);
}

__device__ __forceinline__ float b2f(u16 b) {
  return __uint_as_float(((unsigned)b) << 16);
}

__device__ __forceinline__ void gl_lds16(const void* g, void* l) {
  __builtin_amdgcn_global_load_lds((__attribute__((address_space(1))) void*)g,
                                   (__attribute__((address_space(3))) void*)l, 16, 0, 0);
}

// ---------------- elementwise f32 -> bf16 ----------------
__global__ __launch_bounds__(256) void cvt_f32_bf16(const float* __restrict__ src,
                                                    u16* __restrict__ dst, int n) {
  int i = blockIdx.x * 256 + threadIdx.x;
  const int stride = gridDim.x * 256;
  const int n4 = n >> 2;
  for (; i < n4; i += stride) {
    float4 v = ((const float4*)src)[i];
    ushort4 o;
    o.x = f2bf(v.x); o.y = f2bf(v.y); o.z = f2bf(v.z); o.w = f2bf(v.w);
    ((ushort4*)dst)[i] = o;
  }
}

// ---------------- tiled transpose f32(RxC) -> bf16(CxR) ----------------
__global__ __launch_bounds__(256) void transpose_f32_bf16(const float* __restrict__ src,
                                                          u16* __restrict__ dst, int R, int C) {
  __shared__ float tile[32][33];
  const int tx = threadIdx.x & 31, ty = threadIdx.x >> 5;
  const int r0 = blockIdx.x << 5, c0 = blockIdx.y << 5;
#pragma unroll
  for (int j = 0; j < 4; ++j) {
    int r = r0 + ty + j * 8, c = c0 + tx;
    tile[ty + j * 8][tx] = (r < R && c < C) ? src[(size_t)r * C + c] : 0.f;
  }
  __syncthreads();
#pragma unroll
  for (int j = 0; j < 4; ++j) {
    int cc = c0 + ty + j * 8, rr = r0 + tx;
    if (cc < C && rr < R) dst[(size_t)cc * R + rr] = f2bf(tile[tx][ty + j * 8]);
  }
}

// ---------------- merged transpose of 6 projection weights -> WT ------------------
__global__ __launch_bounds__(256) void transpose_multi(
    const float* __restrict__ s0, const float* __restrict__ s1,
    const float* __restrict__ s2, const float* __restrict__ s3,
    const float* __restrict__ s4, const float* __restrict__ s5,
    u16* __restrict__ WT) {
  const int y = blockIdx.y;
  const float* src; int cofs, C, c0;
  if      (y < 3)  { src = s0; cofs = 0;    C = 96;   c0 = y << 5; }
  else if (y < 4)  { src = s1; cofs = 96;   C = 16;   c0 = 0; }
  else if (y < 5)  { src = s2; cofs = 112;  C = 16;   c0 = 0; }
  else if (y < 53) { src = s3; cofs = 128;  C = 1536; c0 = (y - 5) << 5; }
  else if (y < 69) { src = s4; cofs = 1664; C = 512;  c0 = (y - 53) << 5; }
  else             { src = s5; cofs = 2176; C = 512;  c0 = (y - 69) << 5; }
  u16* dst = WT + (size_t)cofs * HID_;
  __shared__ float tile[32][33];
  const int tx = threadIdx.x & 31, ty = threadIdx.x >> 5;
  const int r0 = blockIdx.x << 5;
#pragma unroll
  for (int j = 0; j < 4; ++j) {
    int r = r0 + ty + j * 8, c = c0 + tx;
    tile[ty + j * 8][tx] = (c < C) ? src[(size_t)r * C + c] : 0.f;
  }
  __syncthreads();
#pragma unroll
  for (int j = 0; j < 4; ++j) {
    int cc = c0 + ty + j * 8, rr = r0 + tx;
    if (cc < C) dst[(size_t)cc * HID_ + rr] = f2bf(tile[tx][ty + j * 8]);
  }
}

// ---------------- tiled transpose bf16(RxC)->bf16(CxR), batched z ----------------
__global__ __launch_bounds__(256) void transpose_bf16_b(const u16* __restrict__ src,
                                                        u16* __restrict__ dst, int R, int C) {
  __shared__ u16 tile[32][34];
  const size_t plane = (size_t)R * C;
  const u16* s = src + (size_t)blockIdx.z * plane;
  u16* d = dst + (size_t)blockIdx.z * plane;
  const int tx = threadIdx.x & 31, ty = threadIdx.x >> 5;
  const int r0 = blockIdx.x << 5, c0 = blockIdx.y << 5;
#pragma unroll
  for (int j = 0; j < 4; ++j) {
    int r = r0 + ty + j * 8, c = c0 + tx;
    tile[ty + j * 8][tx] = (r < R && c < C) ? s[(size_t)r * C + c] : (u16)0;
  }
  __syncthreads();
#pragma unroll
  for (int j = 0; j < 4; ++j) {
    int cc = c0 + ty + j * 8, rr = r0 + tx;
    if (cc < C && rr < R) d[(size_t)cc * R + rr] = tile[tx][ty + j * 8];
  }
}

// ---------------- 256x256 GEMM, BK=32, 4-slot LDS ring, deep counted-vmcnt --------
__global__ __launch_bounds__(512, 1)
void gemm256(const u16* __restrict__ A, const u16* __restrict__ Bm, void* __restrict__ Cv,
             int N, int lda, int ldb, int ldc, int NT, int GY, int obf) {
  __shared__ __align__(16) u16 ring[4][2][8192];
  const int t = threadIdx.x;
  const int lane = t & 63;
  const int lq = lane & 15, lg = lane >> 4;
  const int w = t >> 6;
  const int wm = w >> 2, wn = w & 3;

  const int wg = blockIdx.x;
  const int chunk = gridDim.x >> 3;
  const int gid = (wg & 7) * chunk + (wg >> 3);
  const int bm0 = (gid / GY) * 256, bn0 = (gid % GY) * 256;

  const int rsub = lane >> 2;
  const int ksub = (((lane & 3) ^ ((lane >> 3) & 3)) << 3);
  const u16* paw = A + (size_t)(bm0 + w * 32 + rsub) * lda + ksub;
  const u16* pbw = Bm + (size_t)(bn0 + w * 32 + rsub) * ldb + ksub;

  const int rdo = lq * 32 + ((lg ^ ((lq >> 1) & 3)) << 3);

  f32x4 zero = {0.f, 0.f, 0.f, 0.f};
  f32x4 acc[8][4];
#pragma unroll
  for (int m = 0; m < 8; ++m)
#pragma unroll
    for (int n = 0; n < 4; ++n) acc[m][n] = zero;

#define STAGE_(T)                                                              \
  {                                                                            \
    const int slot_ = (T) & 3;                                                 \
    const size_t ko_ = (size_t)(T) * 32;                                       \
    gl_lds16(paw + ko_,            &ring[slot_][0][(2 * w + 0) * 512]);        \
    gl_lds16(paw + 16 * lda + ko_, &ring[slot_][0][(2 * w + 1) * 512]);        \
    gl_lds16(pbw + ko_,            &ring[slot_][1][(2 * w + 0) * 512]);        \
    gl_lds16(pbw + 16 * ldb + ko_, &ring[slot_][1][(2 * w + 1) * 512]);        \
  }

  STAGE_(0);
  STAGE_(1);
  STAGE_(2);
  asm volatile("s_waitcnt vmcnt(8)" ::: "memory");
  __builtin_amdgcn_s_barrier();

  for (int T = 0; T < NT; ++T) {
    __builtin_amdgcn_sched_barrier(0);
    const int s = T & 3;
    const u16* as = &ring[s][0][wm * 4096];
    const u16* bs = &ring[s][1][wn * 2048];
    short8 af[8], bf[4];
#pragma unroll
    for (int m = 0; m < 8; ++m) af[m] = *(const short8*)(as + m * 512 + rdo);
#pragma unroll
    for (int n = 0; n < 4; ++n) bf[n] = *(const short8*)(bs + n * 512 + rdo);
    if (T + 3 < NT) STAGE_(T + 3);
    __builtin_amdgcn_s_setprio(1);
#pragma unroll
    for (int m = 0; m < 8; ++m)
#pragma unroll
      for (int n = 0; n < 4; ++n)
        acc[m][n] = __builtin_amdgcn_mfma_f32_16x16x32_bf16(af[m], bf[n], acc[m][n], 0, 0, 0);
    __builtin_amdgcn_s_setprio(0);
    if (T + 3 < NT)      { asm volatile("s_waitcnt vmcnt(8) lgkmcnt(0)" ::: "memory"); }
    else if (T + 2 < NT) { asm volatile("s_waitcnt vmcnt(4) lgkmcnt(0)" ::: "memory"); }
    else if (T + 1 < NT) { asm volatile("s_waitcnt vmcnt(0) lgkmcnt(0)" ::: "memory"); }
    else                 { asm volatile("s_waitcnt lgkmcnt(0)" ::: "memory"); }
    __builtin_amdgcn_s_barrier();
  }
#undef STAGE_

#pragma unroll
  for (int m = 0; m < 8; ++m) {
    const int row = bm0 + wm * 128 + m * 16 + lg * 4;
#pragma unroll
    for (int n = 0; n < 4; ++n) {
      const int col = bn0 + wn * 64 + n * 16 + lq;
      if (col < N) {
        if (obf) {
          u16* cp = (u16*)Cv + (size_t)row * ldc + col;
          cp[0] = f2bf(acc[m][n][0]);
          cp[(size_t)ldc] = f2bf(acc[m][n][1]);
          cp[(size_t)2 * ldc] = f2bf(acc[m][n][2]);
          cp[(size_t)3 * ldc] = f2bf(acc[m][n][3]);
        } else {
          float* cp = (float*)Cv + (size_t)row * ldc + col;
          cp[0] = acc[m][n][0];
          cp[(size_t)ldc] = acc[m][n][1];
          cp[(size_t)2 * ldc] = acc[m][n][2];
          cp[(size_t)3 * ldc] = acc[m][n][3];
        }
      }
    }
  }
}

// ---------------- per-token RMSNorm + RoPE + rank contraction -> Q,K,V (bf16) ------
__global__ __launch_bounds__(256)
void build_qkv(const u16* __restrict__ P, const float* __restrict__ freqs,
               const float* __restrict__ qw, const float* __restrict__ kw,
               u16* __restrict__ Qg, u16* __restrict__ Kg, u16* __restrict__ Vg) {
  const int token = blockIdx.x;
  const int b = token >> 11, s = token & 2047;
  const int d = threadIdx.x;
  const u16* row = P + (size_t)token * NPROJ;
  __shared__ float aL[128];
  __shared__ float rQ[6][256];
  __shared__ float rK[2][256];
  __shared__ float red[4][8];

  if (d < 128) aL[d] = b2f(row[d]);
  float bq[6], bk[2], bv[2];
#pragma unroll
  for (int r = 0; r < 6; ++r) bq[r] = b2f(row[128 + r * 256 + d]);
#pragma unroll
  for (int r = 0; r < 2; ++r) bk[r] = b2f(row[1664 + r * 256 + d]);
#pragma unroll
  for (int r = 0; r < 2; ++r) bv[r] = b2f(row[2176 + r * 256 + d]);

  float sq[8];
#pragma unroll
  for (int r = 0; r < 6; ++r) sq[r] = bq[r] * bq[r];
  sq[6] = bk[0] * bk[0];
  sq[7] = bk[1] * bk[1];
#pragma unroll
  for (int j = 0; j < 8; ++j) {
    sq[j] += __shfl_xor(sq[j], 32, 64);
    sq[j] += __shfl_xor(sq[j], 16, 64);
    sq[j] += __shfl_xor(sq[j], 8, 64);
    sq[j] += __shfl_xor(sq[j], 4, 64);
    sq[j] += __shfl_xor(sq[j], 2, 64);
    sq[j] += __shfl_xor(sq[j], 1, 64);
  }
  const int lane = d & 63, wv = d >> 6;
  if (lane == 0) {
#pragma unroll
    for (int j = 0; j < 8; ++j) red[wv][j] = sq[j];
  }
  __syncthreads();
  float inv[8];
#pragma unroll
  for (int j = 0; j < 8; ++j) {
    float ss = red[0][j] + red[1][j] + red[2][j] + red[3][j];
    inv[j] = rsqrtf(ss * (1.0f / 256.0f) + EPS_);
  }
  const float gq = 1.f + qw[d], gk = 1.f + kw[d];
#pragma unroll
  for (int r = 0; r < 6; ++r) rQ[r][d] = bq[r] * inv[r] * gq;
#pragma unroll
  for (int r = 0; r < 2; ++r) rK[r][d] = bk[r] * inv[6 + r] * gk;
  __syncthreads();

  const int dh = d & 127;
  const float co = freqs[(s * 128 + dh) * 2 + 0];
  const float sn = freqs[(s * 128 + dh) * 2 + 1];
  float q_ro[6], k_ro[2];
  if (d < 128) {
#pragma unroll
    for (int r = 0; r < 6; ++r) q_ro[r] = rQ[r][d] * co - rQ[r][d + 128] * sn;
#pragma unroll
    for (int r = 0; r < 2; ++r) k_ro[r] = rK[r][d] * co - rK[r][d + 128] * sn;
  } else {
#pragma unroll
    for (int r = 0; r < 6; ++r) q_ro[r] = rQ[r][d] * co + rQ[r][d - 128] * sn;
#pragma unroll
    for (int r = 0; r < 2; ++r) k_ro[r] = rK[r][d] * co + rK[r][d - 128] * sn;
  }
  const float qs = SCALE_ * (1.0f / 6.0f);
#pragma unroll
  for (int h = 0; h < 16; ++h) {
    float a = 0.f;
#pragma unroll
    for (int r = 0; r < 6; ++r) a += aL[h * 6 + r] * q_ro[r];
    Qg[((size_t)(b * H_ + h) * S_ + s) * D_ + d] = f2bf(a * qs);
  }
#pragma unroll
  for (int kv = 0; kv < 8; ++kv) {
    float ak = aL[96 + kv * 2] * k_ro[0] + aL[96 + kv * 2 + 1] * k_ro[1];
    Kg[((size_t)(b * KV_ + kv) * S_ + s) * D_ + d] = f2bf(ak * 0.5f);
    float av = aL[112 + kv * 2] * bv[0] + aL[112 + kv * 2 + 1] * bv[1];
    Vg[((size_t)(b * KV_ + kv) * S_ + s) * D_ + d] = f2bf(av * 0.5f);
  }
}

// ---------------- flash attention v3+T12: 256 thr, 1 head, KVB=32 -----------------
// T12: P redistributed in-register (cvt_pk + shfl) instead of LDS roundtrip.
// h0 param allows h-range splitting across launches (gemm counter visibility).
__global__ __launch_bounds__(256, 2)
void attn_kernel(const u16* __restrict__ Qg, const u16* __restrict__ Kg,
                 const u16* __restrict__ VTg, u16* __restrict__ Og, int h0) {
  __shared__ __align__(16) u16 Kbuf[2][8192];
  __shared__ __align__(16) u16 Vbuf[2][8192];

  const int t = threadIdx.x;
  const int lane = t & 63;
  const int lq = lane & 15, lg = lane >> 4;
  const int qw = t >> 6;
  const int h = blockIdx.x + h0, b = blockIdx.y;
  const int qt = 31 - blockIdx.z;
  const int q0 = qt * 64;
  const int kvh = h >> 1;

  const u16* Kplane = Kg + (size_t)(b * KV_ + kvh) * S_ * D_;
  const u16* VTplane = VTg + (size_t)(b * KV_ + kvh) * D_ * S_;

  const int qg = q0 + qw * 16 + lq;
  const u16* Qrow = Qg + ((size_t)(b * H_ + h) * S_ + qg) * D_;
  short8 qf[8];
#pragma unroll
  for (int ks = 0; ks < 8; ++ks) qf[ks] = *(const short8*)(Qrow + ks * 32 + lg * 8);

  int ksrc[4], vsrc[4];
#pragma unroll
  for (int i = 0; i < 4; ++i) {
    const int kr = i * 8 + (t >> 5);
    ksrc[i] = kr * D_ + (((t & 31) ^ (kr & 7)) << 3);
    const int vr = i * 64 + (t >> 2);
    vsrc[i] = vr * S_ + (((t & 3) ^ ((vr >> 1) & 3)) << 3);
  }

  f32x4 zero = {0.f, 0.f, 0.f, 0.f};
  f32x4 oacc[16];
#pragma unroll
  for (int db = 0; db < 16; ++db) oacc[db] = zero;
  float m_s = NEG_, l_s = 0.f;

  const int qro = q0 + qw * 16 + lg * 4;
  const int nt = 2 * (qt + 1);

  // T12 redistribution constants
  const int s0l = ((lg & 1) << 5) + lq;   // source lane A (lg_src = 2*(lg&1))
  const int s1l = s0l + 16;               // source lane B (lg_src = 2*(lg&1)+1)
  const bool hi = ((lg >> 1) & 1) != 0;   // take kb=1 regs when true

#pragma unroll
  for (int i = 0; i < 4; ++i) {
    gl_lds16(Kplane + ksrc[i], &Kbuf[0][0] + (i * 256 + t) * 8);
    gl_lds16(VTplane + vsrc[i], &Vbuf[0][0] + (i * 256 + t) * 8);
  }
  __syncthreads();
  int cur = 0;
  for (int it = 0; it < nt; ++it) {
    const int kv0 = it * 32;
    if (it + 1 < nt) {
      const u16* kp = Kplane + (size_t)(it + 1) * 32 * D_;
      const u16* vp = VTplane + (it + 1) * 32;
      u16* kd = &Kbuf[cur ^ 1][0];
      u16* vd = &Vbuf[cur ^ 1][0];
#pragma unroll
      for (int i = 0; i < 4; ++i) {
        gl_lds16(kp + ksrc[i], kd + (i * 256 + t) * 8);
        gl_lds16(vp + vsrc[i], vd + (i * 256 + t) * 8);
      }
    }
    const u16* Kb = &Kbuf[cur][0];
    f32x4 sacc[2];
    sacc[0] = zero; sacc[1] = zero;
    __builtin_amdgcn_s_setprio(1);
#pragma unroll
    for (int kb = 0; kb < 2; ++kb) {
      const int rbase = (kb * 16 + lq) * 256;
      const int sw = lq & 7;
#pragma unroll
      for (int ks = 0; ks < 8; ++ks) {
        short8 kf = *(const short8*)(Kb + rbase + (((ks * 4 + lg) ^ sw) << 3));
        sacc[kb] = __builtin_amdgcn_mfma_f32_16x16x32_bf16(kf, qf[ks], sacc[kb], 0, 0, 0);
      }
    }
    __builtin_amdgcn_s_setprio(0);
    const bool tail = (it >= 2 * qt);
#pragma unroll
    for (int kb = 0; kb < 2; ++kb)
#pragma unroll
      for (int r = 0; r < 4; ++r) {
        float x = sacc[kb][r];
        const float e = __expf(-fabsf(x) * 0.04f);
        const float th = (1.f - e) * __builtin_amdgcn_rcpf(1.f + e);
        x = copysignf(50.0f * th, x);
        if (tail && (kv0 + kb * 16 + lg * 4 + r > qg)) x = NEG_;
        sacc[kb][r] = x;
      }
    float vmax = fmaxf(fmaxf(fmaxf(sacc[0][0], sacc[0][1]), fmaxf(sacc[0][2], sacc[0][3])),
                       fmaxf(fmaxf(sacc[1][0], sacc[1][1]), fmaxf(sacc[1][2], sacc[1][3])));
    vmax = fmaxf(vmax, __shfl_xor(vmax, 16, 64));
    vmax = fmaxf(vmax, __shfl_xor(vmax, 32, 64));
    if (__any(vmax > m_s + 8.f)) {
      const float mn = fmaxf(m_s, vmax);
      const float c = __expf(m_s - mn);
      m_s = mn;
      l_s *= c;
      float c4[4];
#pragma unroll
      for (int r = 0; r < 4; ++r) c4[r] = __shfl(c, lg * 4 + r, 16);
#pragma unroll
      for (int db = 0; db < 16; ++db) {
        oacc[db][0] *= c4[0]; oacc[db][1] *= c4[1];
        oacc[db][2] *= c4[2]; oacc[db][3] *= c4[3];
      }
    }
    float ps = 0.f;
#pragma unroll
    for (int kb = 0; kb < 2; ++kb)
#pragma unroll
      for (int r = 0; r < 4; ++r) {
        const float p = __expf(sacc[kb][r] - m_s);
        sacc[kb][r] = p;
        ps += p;
      }
    ps += __shfl_xor(ps, 16, 64);
    ps += __shfl_xor(ps, 32, 64);
    l_s += ps;
    // ---- T12: pack P to bf16 dwords in-register and redistribute via shfl ----
    // source lane (lq, lg_src) holds P[kv=kb*16+lg_src*4+r][q=lq]:
    //   A0={kb0,r0,r1} A1={kb0,r2,r3} B0={kb1,r0,r1} B1={kb1,r2,r3}
    // dest lane (lq, lg) needs P[q=lq][kv=8lg+e] e=0..7.
    unsigned A0, A1, B0, B1;
    asm("v_cvt_pk_bf16_f32 %0, %1, %2" : "=v"(A0) : "v"(sacc[0][0]), "v"(sacc[0][1]));
    asm("v_cvt_pk_bf16_f32 %0, %1, %2" : "=v"(A1) : "v"(sacc[0][2]), "v"(sacc[0][3]));
    asm("v_cvt_pk_bf16_f32 %0, %1, %2" : "=v"(B0) : "v"(sacc[1][0]), "v"(sacc[1][1]));
    asm("v_cvt_pk_bf16_f32 %0, %1, %2" : "=v"(B1) : "v"(sacc[1][2]), "v"(sacc[1][3]));
    const unsigned xa0 = __shfl((int)A0, s0l, 64), xb0 = __shfl((int)B0, s0l, 64);
    const unsigned xa1 = __shfl((int)A1, s0l, 64), xb1 = __shfl((int)B1, s0l, 64);
    const unsigned ya0 = __shfl((int)A0, s1l, 64), yb0 = __shfl((int)B0, s1l, 64);
    const unsigned ya1 = __shfl((int)A1, s1l, 64), yb1 = __shfl((int)B1, s1l, 64);
    union { unsigned u[4]; short8 v; } pu;
    pu.u[0] = hi ? xb0 : xa0;
    pu.u[1] = hi ? xb1 : xa1;
    pu.u[2] = hi ? yb0 : ya0;
    pu.u[3] = hi ? yb1 : ya1;
    const short8 pf = pu.v;
    const u16* Vb = &Vbuf[cur][0];
    __builtin_amdgcn_s_setprio(1);
#pragma unroll
    for (int db = 0; db < 16; ++db) {
      const int d = db * 16 + lq;
      short8 vf = *(const short8*)(Vb + d * 32 + ((lg ^ ((lq >> 1) & 3)) << 3));
      oacc[db] = __builtin_amdgcn_mfma_f32_16x16x32_bf16(pf, vf, oacc[db], 0, 0, 0);
    }
    __builtin_amdgcn_s_setprio(0);
    __syncthreads();
    cur ^= 1;
  }
  const float invl = __builtin_amdgcn_rcpf(l_s);
  float inv4[4];
#pragma unroll
  for (int r = 0; r < 4; ++r) inv4[r] = __shfl(invl, lg * 4 + r, 16);
#pragma unroll
  for (int r = 0; r < 4; ++r) {
    u16* orow = Og + (size_t)(b * S_ + qro + r) * HD_ + h * D_;
#pragma unroll
    for (int db = 0; db < 16; ++db) orow[db * 16 + lq] = f2bf(oacc[db][r] * inv4[r]);
  }
}

// ---------------- launcher ----------------
extern "C" void kernel_launch(void* const* d_in, const int* in_sizes, int n_in,
                              void* d_out, int out_size, void* d_ws, size_t ws_size,
                              hipStream_t stream) {
  const float* hs    = (const float*)d_in[0];
  const float* freqs = (const float*)d_in[1];
  const float* W_A_q = (const float*)d_in[8];
  const float* W_A_k = (const float*)d_in[9];
  const float* W_A_v = (const float*)d_in[10];
  const float* W_B_q = (const float*)d_in[11];
  const float* W_B_k = (const float*)d_in[12];
  const float* W_B_v = (const float*)d_in[13];
  const float* Wo    = (const float*)d_in[14];
  const float* qw    = (const float*)d_in[15];
  const float* kw    = (const float*)d_in[16];
  float* out = (float*)d_out;

  char* ws = (char*)d_ws;
  u16* hsb = (u16*)(ws);                    // 4096x3584 bf16
  u16* WT  = (u16*)(ws + 29360128);         // 2688x3584 bf16
  u16* WoT = (u16*)(ws + 48627712);         // 3584x4096 bf16
  u16* Qg  = (u16*)(ws + 77987840);         // (B,H,S,D) bf16
  u16* Kg  = (u16*)(ws + 111542272);        // (B,KV,S,D) bf16
  u16* Vg  = (u16*)(ws + 128319488);        // (B,KV,S,D) bf16
  u16* VTg = (u16*)(ws + 145096704);        // (B,KV,D,S) bf16
  u16* AOg = (u16*)(ws + 161873920);        // (B*S, H*D) bf16
  u16* Pb  = (u16*)d_out;                   // 4096x2688 bf16 scratch inside d_out

  cvt_f32_bf16<<<1024, 256, 0, stream>>>(hs, hsb, MTOK * HID_);
  transpose_multi<<<dim3(112, 85), 256, 0, stream>>>(W_A_q, W_A_k, W_A_v, W_B_q, W_B_k, W_B_v, WT);
  transpose_f32_bf16<<<dim3(128, 112), 256, 0, stream>>>(Wo, WoT, HD_, HID_);

  gemm256<<<176, 512, 0, stream>>>(hsb, WT, Pb, NPROJ, HID_, HID_, NPROJ, 112, 11, 1);
  build_qkv<<<4096, 256, 0, stream>>>(Pb, freqs, qw, kw, Qg, Kg, Vg);
  transpose_bf16_b<<<dim3(64, 8, 16), 256, 0, stream>>>(Vg, VTg, S_, D_);
  attn_kernel<<<dim3(8, 2, 32), 256, 0, stream>>>(Qg, Kg, VTg, AOg, 0);
  attn_kernel<<<dim3(8, 2, 32), 256, 0, stream>>>(Qg, Kg, VTg, AOg, 8);
  gemm256<<<224, 512, 0, stream>>>(AOg, WoT, out, HID_, HD_, HD_, HID_, 128, 14, 0);
}

// Round 13
// 428.877 us; speedup vs baseline: 1.2021x; 1.2021x over previous
//
#include <hip/hip_runtime.h>

// ---------------- problem constants ----------------
#define B_    2
#define S_    2048
#define HID_  3584
#define H_    16
#define KV_   8
#define D_    256
#define RQ_   6
#define NPROJ 2688
#define HD_   4096
#define MTOK  4096
#define EPS_  1e-6f
#define NEG_  -2.3819763e38f
#define SCALE_ 0.0625f   // 256^-0.5

typedef unsigned short u16;
typedef __attribute__((ext_vector_type(8))) short short8;
typedef __attribute__((ext_vector_type(4))) float f32x4;

__device__ __forceinline__ u16 f2bf(float f) {
  unsigned u = __float_as_uint(f);
  u += 0x7fffu + ((u >> 16) & 1u);
  return (u16)(u >> 16);
}

__device__ __forceinline__ float b2f(u16 b) {
  return __uint_as_float(((unsigned)b) << 16);
}

__device__ __forceinline__ void gl_lds16(const void* g, void* l) {
  __builtin_amdgcn_global_load_lds((__attribute__((address_space(1))) void*)g,
                                   (__attribute__((address_space(3))) void*)l, 16, 0, 0);
}

// ---------------- elementwise f32 -> bf16 ----------------
__global__ __launch_bounds__(256) void cvt_f32_bf16(const float* __restrict__ src,
                                                    u16* __restrict__ dst, int n) {
  int i = blockIdx.x * 256 + threadIdx.x;
  const int stride = gridDim.x * 256;
  const int n4 = n >> 2;
  for (; i < n4; i += stride) {
    float4 v = ((const float4*)src)[i];
    ushort4 o;
    o.x = f2bf(v.x); o.y = f2bf(v.y); o.z = f2bf(v.z); o.w = f2bf(v.w);
    ((ushort4*)dst)[i] = o;
  }
}

// ---------------- tiled transpose f32(RxC) -> bf16(CxR) ----------------
__global__ __launch_bounds__(256) void transpose_f32_bf16(const float* __restrict__ src,
                                                          u16* __restrict__ dst, int R, int C) {
  __shared__ float tile[32][33];
  const int tx = threadIdx.x & 31, ty = threadIdx.x >> 5;
  const int r0 = blockIdx.x << 5, c0 = blockIdx.y << 5;
#pragma unroll
  for (int j = 0; j < 4; ++j) {
    int r = r0 + ty + j * 8, c = c0 + tx;
    tile[ty + j * 8][tx] = (r < R && c < C) ? src[(size_t)r * C + c] : 0.f;
  }
  __syncthreads();
#pragma unroll
  for (int j = 0; j < 4; ++j) {
    int cc = c0 + ty + j * 8, rr = r0 + tx;
    if (cc < C && rr < R) dst[(size_t)cc * R + rr] = f2bf(tile[tx][ty + j * 8]);
  }
}

// ---------------- merged transpose of 6 projection weights -> WT ------------------
__global__ __launch_bounds__(256) void transpose_multi(
    const float* __restrict__ s0, const float* __restrict__ s1,
    const float* __restrict__ s2, const float* __restrict__ s3,
    const float* __restrict__ s4, const float* __restrict__ s5,
    u16* __restrict__ WT) {
  const int y = blockIdx.y;
  const float* src; int cofs, C, c0;
  if      (y < 3)  { src = s0; cofs = 0;    C = 96;   c0 = y << 5; }
  else if (y < 4)  { src = s1; cofs = 96;   C = 16;   c0 = 0; }
  else if (y < 5)  { src = s2; cofs = 112;  C = 16;   c0 = 0; }
  else if (y < 53) { src = s3; cofs = 128;  C = 1536; c0 = (y - 5) << 5; }
  else if (y < 69) { src = s4; cofs = 1664; C = 512;  c0 = (y - 53) << 5; }
  else             { src = s5; cofs = 2176; C = 512;  c0 = (y - 69) << 5; }
  u16* dst = WT + (size_t)cofs * HID_;
  __shared__ float tile[32][33];
  const int tx = threadIdx.x & 31, ty = threadIdx.x >> 5;
  const int r0 = blockIdx.x << 5;
#pragma unroll
  for (int j = 0; j < 4; ++j) {
    int r = r0 + ty + j * 8, c = c0 + tx;
    tile[ty + j * 8][tx] = (c < C) ? src[(size_t)r * C + c] : 0.f;
  }
  __syncthreads();
#pragma unroll
  for (int j = 0; j < 4; ++j) {
    int cc = c0 + ty + j * 8, rr = r0 + tx;
    if (cc < C) dst[(size_t)cc * HID_ + rr] = f2bf(tile[tx][ty + j * 8]);
  }
}

// ---------------- tiled transpose bf16(RxC)->bf16(CxR), batched z ----------------
__global__ __launch_bounds__(256) void transpose_bf16_b(const u16* __restrict__ src,
                                                        u16* __restrict__ dst, int R, int C) {
  __shared__ u16 tile[32][34];
  const size_t plane = (size_t)R * C;
  const u16* s = src + (size_t)blockIdx.z * plane;
  u16* d = dst + (size_t)blockIdx.z * plane;
  const int tx = threadIdx.x & 31, ty = threadIdx.x >> 5;
  const int r0 = blockIdx.x << 5, c0 = blockIdx.y << 5;
#pragma unroll
  for (int j = 0; j < 4; ++j) {
    int r = r0 + ty + j * 8, c = c0 + tx;
    tile[ty + j * 8][tx] = (r < R && c < C) ? s[(size_t)r * C + c] : (u16)0;
  }
  __syncthreads();
#pragma unroll
  for (int j = 0; j < 4; ++j) {
    int cc = c0 + ty + j * 8, rr = r0 + tx;
    if (cc < C && rr < R) d[(size_t)cc * R + rr] = tile[tx][ty + j * 8];
  }
}

// ---------------- 256x256 GEMM, BK=32, 4-slot LDS ring, deep counted-vmcnt --------
// R13: per-row read interleave -- bf[0..3] first, af[m] read right before row m's
// MFMAs, so row m+1's ds_read latency hides under row m's matrix work.
__global__ __launch_bounds__(512, 1)
void gemm256(const u16* __restrict__ A, const u16* __restrict__ Bm, void* __restrict__ Cv,
             int N, int lda, int ldb, int ldc, int NT, int GY, int obf) {
  __shared__ __align__(16) u16 ring[4][2][8192];
  const int t = threadIdx.x;
  const int lane = t & 63;
  const int lq = lane & 15, lg = lane >> 4;
  const int w = t >> 6;
  const int wm = w >> 2, wn = w & 3;

  const int wg = blockIdx.x;
  const int chunk = gridDim.x >> 3;
  const int gid = (wg & 7) * chunk + (wg >> 3);
  const int bm0 = (gid / GY) * 256, bn0 = (gid % GY) * 256;

  const int rsub = lane >> 2;
  const int ksub = (((lane & 3) ^ ((lane >> 3) & 3)) << 3);
  const u16* paw = A + (size_t)(bm0 + w * 32 + rsub) * lda + ksub;
  const u16* pbw = Bm + (size_t)(bn0 + w * 32 + rsub) * ldb + ksub;

  const int rdo = lq * 32 + ((lg ^ ((lq >> 1) & 3)) << 3);

  f32x4 zero = {0.f, 0.f, 0.f, 0.f};
  f32x4 acc[8][4];
#pragma unroll
  for (int m = 0; m < 8; ++m)
#pragma unroll
    for (int n = 0; n < 4; ++n) acc[m][n] = zero;

#define STAGE_(T)                                                              \
  {                                                                            \
    const int slot_ = (T) & 3;                                                 \
    const size_t ko_ = (size_t)(T) * 32;                                       \
    gl_lds16(paw + ko_,            &ring[slot_][0][(2 * w + 0) * 512]);        \
    gl_lds16(paw + 16 * lda + ko_, &ring[slot_][0][(2 * w + 1) * 512]);        \
    gl_lds16(pbw + ko_,            &ring[slot_][1][(2 * w + 0) * 512]);        \
    gl_lds16(pbw + 16 * ldb + ko_, &ring[slot_][1][(2 * w + 1) * 512]);        \
  }

  STAGE_(0);
  STAGE_(1);
  STAGE_(2);
  asm volatile("s_waitcnt vmcnt(8)" ::: "memory");
  __builtin_amdgcn_s_barrier();

  for (int T = 0; T < NT; ++T) {
    __builtin_amdgcn_sched_barrier(0);
    const int s = T & 3;
    const u16* as = &ring[s][0][wm * 4096];
    const u16* bs = &ring[s][1][wn * 2048];
    short8 bf[4];
#pragma unroll
    for (int n = 0; n < 4; ++n) bf[n] = *(const short8*)(bs + n * 512 + rdo);
    if (T + 3 < NT) STAGE_(T + 3);
    __builtin_amdgcn_s_setprio(1);
#pragma unroll
    for (int m = 0; m < 8; ++m) {
      const short8 af = *(const short8*)(as + m * 512 + rdo);
#pragma unroll
      for (int n = 0; n < 4; ++n)
        acc[m][n] = __builtin_amdgcn_mfma_f32_16x16x32_bf16(af, bf[n], acc[m][n], 0, 0, 0);
    }
    __builtin_amdgcn_s_setprio(0);
    if (T + 3 < NT)      { asm volatile("s_waitcnt vmcnt(8) lgkmcnt(0)" ::: "memory"); }
    else if (T + 2 < NT) { asm volatile("s_waitcnt vmcnt(4) lgkmcnt(0)" ::: "memory"); }
    else if (T + 1 < NT) { asm volatile("s_waitcnt vmcnt(0) lgkmcnt(0)" ::: "memory"); }
    else                 { asm volatile("s_waitcnt lgkmcnt(0)" ::: "memory"); }
    __builtin_amdgcn_s_barrier();
  }
#undef STAGE_

#pragma unroll
  for (int m = 0; m < 8; ++m) {
    const int row = bm0 + wm * 128 + m * 16 + lg * 4;
#pragma unroll
    for (int n = 0; n < 4; ++n) {
      const int col = bn0 + wn * 64 + n * 16 + lq;
      if (col < N) {
        if (obf) {
          u16* cp = (u16*)Cv + (size_t)row * ldc + col;
          cp[0] = f2bf(acc[m][n][0]);
          cp[(size_t)ldc] = f2bf(acc[m][n][1]);
          cp[(size_t)2 * ldc] = f2bf(acc[m][n][2]);
          cp[(size_t)3 * ldc] = f2bf(acc[m][n][3]);
        } else {
          float* cp = (float*)Cv + (size_t)row * ldc + col;
          cp[0] = acc[m][n][0];
          cp[(size_t)ldc] = acc[m][n][1];
          cp[(size_t)2 * ldc] = acc[m][n][2];
          cp[(size_t)3 * ldc] = acc[m][n][3];
        }
      }
    }
  }
}

// ---------------- per-token RMSNorm + RoPE + rank contraction -> Q,K,V (bf16) ------
__global__ __launch_bounds__(256)
void build_qkv(const u16* __restrict__ P, const float* __restrict__ freqs,
               const float* __restrict__ qw, const float* __restrict__ kw,
               u16* __restrict__ Qg, u16* __restrict__ Kg, u16* __restrict__ Vg) {
  const int token = blockIdx.x;
  const int b = token >> 11, s = token & 2047;
  const int d = threadIdx.x;
  const u16* row = P + (size_t)token * NPROJ;
  __shared__ float aL[128];
  __shared__ float rQ[6][256];
  __shared__ float rK[2][256];
  __shared__ float red[4][8];

  if (d < 128) aL[d] = b2f(row[d]);
  float bq[6], bk[2], bv[2];
#pragma unroll
  for (int r = 0; r < 6; ++r) bq[r] = b2f(row[128 + r * 256 + d]);
#pragma unroll
  for (int r = 0; r < 2; ++r) bk[r] = b2f(row[1664 + r * 256 + d]);
#pragma unroll
  for (int r = 0; r < 2; ++r) bv[r] = b2f(row[2176 + r * 256 + d]);

  float sq[8];
#pragma unroll
  for (int r = 0; r < 6; ++r) sq[r] = bq[r] * bq[r];
  sq[6] = bk[0] * bk[0];
  sq[7] = bk[1] * bk[1];
#pragma unroll
  for (int j = 0; j < 8; ++j) {
    sq[j] += __shfl_xor(sq[j], 32, 64);
    sq[j] += __shfl_xor(sq[j], 16, 64);
    sq[j] += __shfl_xor(sq[j], 8, 64);
    sq[j] += __shfl_xor(sq[j], 4, 64);
    sq[j] += __shfl_xor(sq[j], 2, 64);
    sq[j] += __shfl_xor(sq[j], 1, 64);
  }
  const int lane = d & 63, wv = d >> 6;
  if (lane == 0) {
#pragma unroll
    for (int j = 0; j < 8; ++j) red[wv][j] = sq[j];
  }
  __syncthreads();
  float inv[8];
#pragma unroll
  for (int j = 0; j < 8; ++j) {
    float ss = red[0][j] + red[1][j] + red[2][j] + red[3][j];
    inv[j] = rsqrtf(ss * (1.0f / 256.0f) + EPS_);
  }
  const float gq = 1.f + qw[d], gk = 1.f + kw[d];
#pragma unroll
  for (int r = 0; r < 6; ++r) rQ[r][d] = bq[r] * inv[r] * gq;
#pragma unroll
  for (int r = 0; r < 2; ++r) rK[r][d] = bk[r] * inv[6 + r] * gk;
  __syncthreads();

  const int dh = d & 127;
  const float co = freqs[(s * 128 + dh) * 2 + 0];
  const float sn = freqs[(s * 128 + dh) * 2 + 1];
  float q_ro[6], k_ro[2];
  if (d < 128) {
#pragma unroll
    for (int r = 0; r < 6; ++r) q_ro[r] = rQ[r][d] * co - rQ[r][d + 128] * sn;
#pragma unroll
    for (int r = 0; r < 2; ++r) k_ro[r] = rK[r][d] * co - rK[r][d + 128] * sn;
  } else {
#pragma unroll
    for (int r = 0; r < 6; ++r) q_ro[r] = rQ[r][d] * co + rQ[r][d - 128] * sn;
#pragma unroll
    for (int r = 0; r < 2; ++r) k_ro[r] = rK[r][d] * co + rK[r][d - 128] * sn;
  }
  const float qs = SCALE_ * (1.0f / 6.0f);
#pragma unroll
  for (int h = 0; h < 16; ++h) {
    float a = 0.f;
#pragma unroll
    for (int r = 0; r < 6; ++r) a += aL[h * 6 + r] * q_ro[r];
    Qg[((size_t)(b * H_ + h) * S_ + s) * D_ + d] = f2bf(a * qs);
  }
#pragma unroll
  for (int kv = 0; kv < 8; ++kv) {
    float ak = aL[96 + kv * 2] * k_ro[0] + aL[96 + kv * 2 + 1] * k_ro[1];
    Kg[((size_t)(b * KV_ + kv) * S_ + s) * D_ + d] = f2bf(ak * 0.5f);
    float av = aL[112 + kv * 2] * bv[0] + aL[112 + kv * 2 + 1] * bv[1];
    Vg[((size_t)(b * KV_ + kv) * S_ + s) * D_ + d] = f2bf(av * 0.5f);
  }
}

// ---------------- flash attention v3 (proven 148us): 256 thr, 1 head, KVB=32 ------
__global__ __launch_bounds__(256, 2)
void attn_kernel(const u16* __restrict__ Qg, const u16* __restrict__ Kg,
                 const u16* __restrict__ VTg, u16* __restrict__ Og) {
  __shared__ __align__(16) u16 Kbuf[2][8192];
  __shared__ __align__(16) u16 Vbuf[2][8192];
  __shared__ __align__(16) u16 Pbuf[4][512];

  const int t = threadIdx.x;
  const int lane = t & 63;
  const int lq = lane & 15, lg = lane >> 4;
  const int qw = t >> 6;
  const int h = blockIdx.x, b = blockIdx.y;
  const int qt = 31 - blockIdx.z;
  const int q0 = qt * 64;
  const int kvh = h >> 1;

  const u16* Kplane = Kg + (size_t)(b * KV_ + kvh) * S_ * D_;
  const u16* VTplane = VTg + (size_t)(b * KV_ + kvh) * D_ * S_;

  const int qg = q0 + qw * 16 + lq;
  const u16* Qrow = Qg + ((size_t)(b * H_ + h) * S_ + qg) * D_;
  short8 qf[8];
#pragma unroll
  for (int ks = 0; ks < 8; ++ks) qf[ks] = *(const short8*)(Qrow + ks * 32 + lg * 8);

  int ksrc[4], vsrc[4];
#pragma unroll
  for (int i = 0; i < 4; ++i) {
    const int kr = i * 8 + (t >> 5);
    ksrc[i] = kr * D_ + (((t & 31) ^ (kr & 7)) << 3);
    const int vr = i * 64 + (t >> 2);
    vsrc[i] = vr * S_ + (((t & 3) ^ ((vr >> 1) & 3)) << 3);
  }

  f32x4 zero = {0.f, 0.f, 0.f, 0.f};
  f32x4 oacc[16];
#pragma unroll
  for (int db = 0; db < 16; ++db) oacc[db] = zero;
  float m_s = NEG_, l_s = 0.f;

  const int qro = q0 + qw * 16 + lg * 4;
  const int nt = 2 * (qt + 1);

#pragma unroll
  for (int i = 0; i < 4; ++i) {
    gl_lds16(Kplane + ksrc[i], &Kbuf[0][0] + (i * 256 + t) * 8);
    gl_lds16(VTplane + vsrc[i], &Vbuf[0][0] + (i * 256 + t) * 8);
  }
  __syncthreads();
  int cur = 0;
  for (int it = 0; it < nt; ++it) {
    const int kv0 = it * 32;
    if (it + 1 < nt) {
      const u16* kp = Kplane + (size_t)(it + 1) * 32 * D_;
      const u16* vp = VTplane + (it + 1) * 32;
      u16* kd = &Kbuf[cur ^ 1][0];
      u16* vd = &Vbuf[cur ^ 1][0];
#pragma unroll
      for (int i = 0; i < 4; ++i) {
        gl_lds16(kp + ksrc[i], kd + (i * 256 + t) * 8);
        gl_lds16(vp + vsrc[i], vd + (i * 256 + t) * 8);
      }
    }
    const u16* Kb = &Kbuf[cur][0];
    f32x4 sacc[2];
    sacc[0] = zero; sacc[1] = zero;
    __builtin_amdgcn_s_setprio(1);
#pragma unroll
    for (int kb = 0; kb < 2; ++kb) {
      const int rbase = (kb * 16 + lq) * 256;
      const int sw = lq & 7;
#pragma unroll
      for (int ks = 0; ks < 8; ++ks) {
        short8 kf = *(const short8*)(Kb + rbase + (((ks * 4 + lg) ^ sw) << 3));
        sacc[kb] = __builtin_amdgcn_mfma_f32_16x16x32_bf16(kf, qf[ks], sacc[kb], 0, 0, 0);
      }
    }
    __builtin_amdgcn_s_setprio(0);
    const bool tail = (it >= 2 * qt);
#pragma unroll
    for (int kb = 0; kb < 2; ++kb)
#pragma unroll
      for (int r = 0; r < 4; ++r) {
        float x = sacc[kb][r];
        const float e = __expf(-fabsf(x) * 0.04f);
        const float th = (1.f - e) * __builtin_amdgcn_rcpf(1.f + e);
        x = copysignf(50.0f * th, x);
        if (tail && (kv0 + kb * 16 + lg * 4 + r > qg)) x = NEG_;
        sacc[kb][r] = x;
      }
    float vmax = fmaxf(fmaxf(fmaxf(sacc[0][0], sacc[0][1]), fmaxf(sacc[0][2], sacc[0][3])),
                       fmaxf(fmaxf(sacc[1][0], sacc[1][1]), fmaxf(sacc[1][2], sacc[1][3])));
    vmax = fmaxf(vmax, __shfl_xor(vmax, 16, 64));
    vmax = fmaxf(vmax, __shfl_xor(vmax, 32, 64));
    if (__any(vmax > m_s + 8.f)) {
      const float mn = fmaxf(m_s, vmax);
      const float c = __expf(m_s - mn);
      m_s = mn;
      l_s *= c;
      float c4[4];
#pragma unroll
      for (int r = 0; r < 4; ++r) c4[r] = __shfl(c, lg * 4 + r, 16);
#pragma unroll
      for (int db = 0; db < 16; ++db) {
        oacc[db][0] *= c4[0]; oacc[db][1] *= c4[1];
        oacc[db][2] *= c4[2]; oacc[db][3] *= c4[3];
      }
    }
    float ps = 0.f;
#pragma unroll
    for (int kb = 0; kb < 2; ++kb)
#pragma unroll
      for (int r = 0; r < 4; ++r) {
        const float p = __expf(sacc[kb][r] - m_s);
        sacc[kb][r] = p;
        ps += p;
      }
    ps += __shfl_xor(ps, 16, 64);
    ps += __shfl_xor(ps, 32, 64);
    l_s += ps;
    u16* Pw = &Pbuf[qw][0];
#pragma unroll
    for (int kb = 0; kb < 2; ++kb) {
      ushort4 pk;
      pk.x = f2bf(sacc[kb][0]); pk.y = f2bf(sacc[kb][1]);
      pk.z = f2bf(sacc[kb][2]); pk.w = f2bf(sacc[kb][3]);
      *(ushort4*)(Pw + 8 * lq + 128 * (2 * kb + (lg >> 1)) + 4 * (lg & 1)) = pk;
    }
    short8 pf = *(const short8*)(Pw + lane * 8);
    const u16* Vb = &Vbuf[cur][0];
    __builtin_amdgcn_s_setprio(1);
#pragma unroll
    for (int db = 0; db < 16; ++db) {
      const int d = db * 16 + lq;
      short8 vf = *(const short8*)(Vb + d * 32 + ((lg ^ ((lq >> 1) & 3)) << 3));
      oacc[db] = __builtin_amdgcn_mfma_f32_16x16x32_bf16(pf, vf, oacc[db], 0, 0, 0);
    }
    __builtin_amdgcn_s_setprio(0);
    __syncthreads();
    cur ^= 1;
  }
  const float invl = __builtin_amdgcn_rcpf(l_s);
  float inv4[4];
#pragma unroll
  for (int r = 0; r < 4; ++r) inv4[r] = __shfl(invl, lg * 4 + r, 16);
#pragma unroll
  for (int r = 0; r < 4; ++r) {
    u16* orow = Og + (size_t)(b * S_ + qro + r) * HD_ + h * D_;
#pragma unroll
    for (int db = 0; db < 16; ++db) orow[db * 16 + lq] = f2bf(oacc[db][r] * inv4[r]);
  }
}

// ---------------- launcher ----------------
extern "C" void kernel_launch(void* const* d_in, const int* in_sizes, int n_in,
                              void* d_out, int out_size, void* d_ws, size_t ws_size,
                              hipStream_t stream) {
  const float* hs    = (const float*)d_in[0];
  const float* freqs = (const float*)d_in[1];
  const float* W_A_q = (const float*)d_in[8];
  const float* W_A_k = (const float*)d_in[9];
  const float* W_A_v = (const float*)d_in[10];
  const float* W_B_q = (const float*)d_in[11];
  const float* W_B_k = (const float*)d_in[12];
  const float* W_B_v = (const float*)d_in[13];
  const float* Wo    = (const float*)d_in[14];
  const float* qw    = (const float*)d_in[15];
  const float* kw    = (const float*)d_in[16];
  float* out = (float*)d_out;

  char* ws = (char*)d_ws;
  u16* hsb = (u16*)(ws);                    // 4096x3584 bf16
  u16* WT  = (u16*)(ws + 29360128);         // 2688x3584 bf16
  u16* WoT = (u16*)(ws + 48627712);         // 3584x4096 bf16
  u16* Qg  = (u16*)(ws + 77987840);         // (B,H,S,D) bf16
  u16* Kg  = (u16*)(ws + 111542272);        // (B,KV,S,D) bf16
  u16* Vg  = (u16*)(ws + 128319488);        // (B,KV,S,D) bf16
  u16* VTg = (u16*)(ws + 145096704);        // (B,KV,D,S) bf16
  u16* AOg = (u16*)(ws + 161873920);        // (B*S, H*D) bf16
  u16* Pb  = (u16*)d_out;                   // 4096x2688 bf16 scratch inside d_out

  cvt_f32_bf16<<<1024, 256, 0, stream>>>(hs, hsb, MTOK * HID_);
  transpose_multi<<<dim3(112, 85), 256, 0, stream>>>(W_A_q, W_A_k, W_A_v, W_B_q, W_B_k, W_B_v, WT);
  transpose_f32_bf16<<<dim3(128, 112), 256, 0, stream>>>(Wo, WoT, HD_, HID_);

  gemm256<<<176, 512, 0, stream>>>(hsb, WT, Pb, NPROJ, HID_, HID_, NPROJ, 112, 11, 1);
  build_qkv<<<4096, 256, 0, stream>>>(Pb, freqs, qw, kw, Qg, Kg, Vg);
  transpose_bf16_b<<<dim3(64, 8, 16), 256, 0, stream>>>(Vg, VTg, S_, D_);
  attn_kernel<<<dim3(16, 2, 32), 256, 0, stream>>>(Qg, Kg, VTg, AOg);
  gemm256<<<224, 512, 0, stream>>>(AOg, WoT, out, HID_, HD_, HD_, HID_, 128, 14, 0);
}

// Round 14
// 414.502 us; speedup vs baseline: 1.2438x; 1.0347x over previous
//
#include <hip/hip_runtime.h>

// ---------------- problem constants ----------------
#define B_    2
#define S_    2048
#define HID_  3584
#define H_    16
#define KV_   8
#define D_    256
#define RQ_   6
#define NPROJ 2688
#define HD_   4096
#define MTOK  4096
#define EPS_  1e-6f
#define NEG_  -2.3819763e38f
#define SCALE_ 0.0625f   // 256^-0.5

typedef unsigned short u16;
typedef __attribute__((ext_vector_type(8))) short short8;
typedef __attribute__((ext_vector_type(4))) float f32x4;

__device__ __forceinline__ u16 f2bf(float f) {
  unsigned u = __float_as_uint(f);
  u += 0x7fffu + ((u >> 16) & 1u);
  return (u16)(u >> 16);
}

__device__ __forceinline__ float b2f(u16 b) {
  return __uint_as_float(((unsigned)b) << 16);
}

__device__ __forceinline__ void gl_lds16(const void* g, void* l) {
  __builtin_amdgcn_global_load_lds((__attribute__((address_space(1))) void*)g,
                                   (__attribute__((address_space(3))) void*)l, 16, 0, 0);
}

// ---------------- elementwise f32 -> bf16 ----------------
__global__ __launch_bounds__(256) void cvt_f32_bf16(const float* __restrict__ src,
                                                    u16* __restrict__ dst, int n) {
  int i = blockIdx.x * 256 + threadIdx.x;
  const int stride = gridDim.x * 256;
  const int n4 = n >> 2;
  for (; i < n4; i += stride) {
    float4 v = ((const float4*)src)[i];
    ushort4 o;
    o.x = f2bf(v.x); o.y = f2bf(v.y); o.z = f2bf(v.z); o.w = f2bf(v.w);
    ((ushort4*)dst)[i] = o;
  }
}

// ---------------- tiled transpose f32(RxC) -> bf16(CxR) ----------------
__global__ __launch_bounds__(256) void transpose_f32_bf16(const float* __restrict__ src,
                                                          u16* __restrict__ dst, int R, int C) {
  __shared__ float tile[32][33];
  const int tx = threadIdx.x & 31, ty = threadIdx.x >> 5;
  const int r0 = blockIdx.x << 5, c0 = blockIdx.y << 5;
#pragma unroll
  for (int j = 0; j < 4; ++j) {
    int r = r0 + ty + j * 8, c = c0 + tx;
    tile[ty + j * 8][tx] = (r < R && c < C) ? src[(size_t)r * C + c] : 0.f;
  }
  __syncthreads();
#pragma unroll
  for (int j = 0; j < 4; ++j) {
    int cc = c0 + ty + j * 8, rr = r0 + tx;
    if (cc < C && rr < R) dst[(size_t)cc * R + rr] = f2bf(tile[tx][ty + j * 8]);
  }
}

// ---------------- merged transpose of 6 projection weights -> WT ------------------
__global__ __launch_bounds__(256) void transpose_multi(
    const float* __restrict__ s0, const float* __restrict__ s1,
    const float* __restrict__ s2, const float* __restrict__ s3,
    const float* __restrict__ s4, const float* __restrict__ s5,
    u16* __restrict__ WT) {
  const int y = blockIdx.y;
  const float* src; int cofs, C, c0;
  if      (y < 3)  { src = s0; cofs = 0;    C = 96;   c0 = y << 5; }
  else if (y < 4)  { src = s1; cofs = 96;   C = 16;   c0 = 0; }
  else if (y < 5)  { src = s2; cofs = 112;  C = 16;   c0 = 0; }
  else if (y < 53) { src = s3; cofs = 128;  C = 1536; c0 = (y - 5) << 5; }
  else if (y < 69) { src = s4; cofs = 1664; C = 512;  c0 = (y - 53) << 5; }
  else             { src = s5; cofs = 2176; C = 512;  c0 = (y - 69) << 5; }
  u16* dst = WT + (size_t)cofs * HID_;
  __shared__ float tile[32][33];
  const int tx = threadIdx.x & 31, ty = threadIdx.x >> 5;
  const int r0 = blockIdx.x << 5;
#pragma unroll
  for (int j = 0; j < 4; ++j) {
    int r = r0 + ty + j * 8, c = c0 + tx;
    tile[ty + j * 8][tx] = (c < C) ? src[(size_t)r * C + c] : 0.f;
  }
  __syncthreads();
#pragma unroll
  for (int j = 0; j < 4; ++j) {
    int cc = c0 + ty + j * 8, rr = r0 + tx;
    if (cc < C) dst[(size_t)cc * HID_ + rr] = f2bf(tile[tx][ty + j * 8]);
  }
}

// ---------------- vectorized bf16 transpose: (S_ x D_) -> (D_ x S_), batched z -----
// 64x64 tiles, ushort4 global reads+writes (G13), LDS pad 70 -> 2-way banks (free).
__global__ __launch_bounds__(256) void transpose_bf16_v(const u16* __restrict__ src,
                                                        u16* __restrict__ dst) {
  __shared__ u16 tile[64][70];
  const size_t plane = (size_t)S_ * D_;
  const u16* s = src + (size_t)blockIdx.z * plane;
  u16* d = dst + (size_t)blockIdx.z * plane;
  const int t = threadIdx.x;
  const int r0 = blockIdx.x << 6;          // s-tile base (S_ rows)
  const int c0 = blockIdx.y << 6;          // d-tile base (D_ cols)
  const int cx = (t & 15) << 2;            // col within tile, x4
  const int rg = t >> 4;                   // row group 0..15
#pragma unroll
  for (int jj = 0; jj < 4; ++jj) {
    const int row = rg + jj * 16;
    const ushort4 v = *(const ushort4*)(s + (size_t)(r0 + row) * D_ + c0 + cx);
    tile[row][cx + 0] = v.x; tile[row][cx + 1] = v.y;
    tile[row][cx + 2] = v.z; tile[row][cx + 3] = v.w;
  }
  __syncthreads();
#pragma unroll
  for (int jj = 0; jj < 4; ++jj) {
    const int crow = rg + jj * 16;         // output row = d index within tile
    ushort4 o;
    o.x = tile[cx + 0][crow]; o.y = tile[cx + 1][crow];
    o.z = tile[cx + 2][crow]; o.w = tile[cx + 3][crow];
    *(ushort4*)(d + (size_t)(c0 + crow) * S_ + r0 + cx) = o;
  }
}

// ---------------- 256x256 GEMM, BK=32, 4-slot LDS ring, deep counted-vmcnt --------
// (reverted byte-for-byte to R11 read order: af[0..7] then bf[0..3])
__global__ __launch_bounds__(512, 1)
void gemm256(const u16* __restrict__ A, const u16* __restrict__ Bm, void* __restrict__ Cv,
             int N, int lda, int ldb, int ldc, int NT, int GY, int obf) {
  __shared__ __align__(16) u16 ring[4][2][8192];
  const int t = threadIdx.x;
  const int lane = t & 63;
  const int lq = lane & 15, lg = lane >> 4;
  const int w = t >> 6;
  const int wm = w >> 2, wn = w & 3;

  const int wg = blockIdx.x;
  const int chunk = gridDim.x >> 3;
  const int gid = (wg & 7) * chunk + (wg >> 3);
  const int bm0 = (gid / GY) * 256, bn0 = (gid % GY) * 256;

  const int rsub = lane >> 2;
  const int ksub = (((lane & 3) ^ ((lane >> 3) & 3)) << 3);
  const u16* paw = A + (size_t)(bm0 + w * 32 + rsub) * lda + ksub;
  const u16* pbw = Bm + (size_t)(bn0 + w * 32 + rsub) * ldb + ksub;

  const int rdo = lq * 32 + ((lg ^ ((lq >> 1) & 3)) << 3);

  f32x4 zero = {0.f, 0.f, 0.f, 0.f};
  f32x4 acc[8][4];
#pragma unroll
  for (int m = 0; m < 8; ++m)
#pragma unroll
    for (int n = 0; n < 4; ++n) acc[m][n] = zero;

#define STAGE_(T)                                                              \
  {                                                                            \
    const int slot_ = (T) & 3;                                                 \
    const size_t ko_ = (size_t)(T) * 32;                                       \
    gl_lds16(paw + ko_,            &ring[slot_][0][(2 * w + 0) * 512]);        \
    gl_lds16(paw + 16 * lda + ko_, &ring[slot_][0][(2 * w + 1) * 512]);        \
    gl_lds16(pbw + ko_,            &ring[slot_][1][(2 * w + 0) * 512]);        \
    gl_lds16(pbw + 16 * ldb + ko_, &ring[slot_][1][(2 * w + 1) * 512]);        \
  }

  STAGE_(0);
  STAGE_(1);
  STAGE_(2);
  asm volatile("s_waitcnt vmcnt(8)" ::: "memory");
  __builtin_amdgcn_s_barrier();

  for (int T = 0; T < NT; ++T) {
    __builtin_amdgcn_sched_barrier(0);
    const int s = T & 3;
    const u16* as = &ring[s][0][wm * 4096];
    const u16* bs = &ring[s][1][wn * 2048];
    short8 af[8], bf[4];
#pragma unroll
    for (int m = 0; m < 8; ++m) af[m] = *(const short8*)(as + m * 512 + rdo);
#pragma unroll
    for (int n = 0; n < 4; ++n) bf[n] = *(const short8*)(bs + n * 512 + rdo);
    if (T + 3 < NT) STAGE_(T + 3);
    __builtin_amdgcn_s_setprio(1);
#pragma unroll
    for (int m = 0; m < 8; ++m)
#pragma unroll
      for (int n = 0; n < 4; ++n)
        acc[m][n] = __builtin_amdgcn_mfma_f32_16x16x32_bf16(af[m], bf[n], acc[m][n], 0, 0, 0);
    __builtin_amdgcn_s_setprio(0);
    if (T + 3 < NT)      { asm volatile("s_waitcnt vmcnt(8) lgkmcnt(0)" ::: "memory"); }
    else if (T + 2 < NT) { asm volatile("s_waitcnt vmcnt(4) lgkmcnt(0)" ::: "memory"); }
    else if (T + 1 < NT) { asm volatile("s_waitcnt vmcnt(0) lgkmcnt(0)" ::: "memory"); }
    else                 { asm volatile("s_waitcnt lgkmcnt(0)" ::: "memory"); }
    __builtin_amdgcn_s_barrier();
  }
#undef STAGE_

#pragma unroll
  for (int m = 0; m < 8; ++m) {
    const int row = bm0 + wm * 128 + m * 16 + lg * 4;
#pragma unroll
    for (int n = 0; n < 4; ++n) {
      const int col = bn0 + wn * 64 + n * 16 + lq;
      if (col < N) {
        if (obf) {
          u16* cp = (u16*)Cv + (size_t)row * ldc + col;
          cp[0] = f2bf(acc[m][n][0]);
          cp[(size_t)ldc] = f2bf(acc[m][n][1]);
          cp[(size_t)2 * ldc] = f2bf(acc[m][n][2]);
          cp[(size_t)3 * ldc] = f2bf(acc[m][n][3]);
        } else {
          float* cp = (float*)Cv + (size_t)row * ldc + col;
          cp[0] = acc[m][n][0];
          cp[(size_t)ldc] = acc[m][n][1];
          cp[(size_t)2 * ldc] = acc[m][n][2];
          cp[(size_t)3 * ldc] = acc[m][n][3];
        }
      }
    }
  }
}

// ---------------- per-token RMSNorm + RoPE + rank contraction -> Q,K,V (bf16) ------
__global__ __launch_bounds__(256)
void build_qkv(const u16* __restrict__ P, const float* __restrict__ freqs,
               const float* __restrict__ qw, const float* __restrict__ kw,
               u16* __restrict__ Qg, u16* __restrict__ Kg, u16* __restrict__ Vg) {
  const int token = blockIdx.x;
  const int b = token >> 11, s = token & 2047;
  const int d = threadIdx.x;
  const u16* row = P + (size_t)token * NPROJ;
  __shared__ float aL[128];
  __shared__ float rQ[6][256];
  __shared__ float rK[2][256];
  __shared__ float red[4][8];

  if (d < 128) aL[d] = b2f(row[d]);
  float bq[6], bk[2], bv[2];
#pragma unroll
  for (int r = 0; r < 6; ++r) bq[r] = b2f(row[128 + r * 256 + d]);
#pragma unroll
  for (int r = 0; r < 2; ++r) bk[r] = b2f(row[1664 + r * 256 + d]);
#pragma unroll
  for (int r = 0; r < 2; ++r) bv[r] = b2f(row[2176 + r * 256 + d]);

  float sq[8];
#pragma unroll
  for (int r = 0; r < 6; ++r) sq[r] = bq[r] * bq[r];
  sq[6] = bk[0] * bk[0];
  sq[7] = bk[1] * bk[1];
#pragma unroll
  for (int j = 0; j < 8; ++j) {
    sq[j] += __shfl_xor(sq[j], 32, 64);
    sq[j] += __shfl_xor(sq[j], 16, 64);
    sq[j] += __shfl_xor(sq[j], 8, 64);
    sq[j] += __shfl_xor(sq[j], 4, 64);
    sq[j] += __shfl_xor(sq[j], 2, 64);
    sq[j] += __shfl_xor(sq[j], 1, 64);
  }
  const int lane = d & 63, wv = d >> 6;
  if (lane == 0) {
#pragma unroll
    for (int j = 0; j < 8; ++j) red[wv][j] = sq[j];
  }
  __syncthreads();
  float inv[8];
#pragma unroll
  for (int j = 0; j < 8; ++j) {
    float ss = red[0][j] + red[1][j] + red[2][j] + red[3][j];
    inv[j] = rsqrtf(ss * (1.0f / 256.0f) + EPS_);
  }
  const float gq = 1.f + qw[d], gk = 1.f + kw[d];
#pragma unroll
  for (int r = 0; r < 6; ++r) rQ[r][d] = bq[r] * inv[r] * gq;
#pragma unroll
  for (int r = 0; r < 2; ++r) rK[r][d] = bk[r] * inv[6 + r] * gk;
  __syncthreads();

  const int dh = d & 127;
  const float co = freqs[(s * 128 + dh) * 2 + 0];
  const float sn = freqs[(s * 128 + dh) * 2 + 1];
  float q_ro[6], k_ro[2];
  if (d < 128) {
#pragma unroll
    for (int r = 0; r < 6; ++r) q_ro[r] = rQ[r][d] * co - rQ[r][d + 128] * sn;
#pragma unroll
    for (int r = 0; r < 2; ++r) k_ro[r] = rK[r][d] * co - rK[r][d + 128] * sn;
  } else {
#pragma unroll
    for (int r = 0; r < 6; ++r) q_ro[r] = rQ[r][d] * co + rQ[r][d - 128] * sn;
#pragma unroll
    for (int r = 0; r < 2; ++r) k_ro[r] = rK[r][d] * co + rK[r][d - 128] * sn;
  }
  const float qs = SCALE_ * (1.0f / 6.0f);
#pragma unroll
  for (int h = 0; h < 16; ++h) {
    float a = 0.f;
#pragma unroll
    for (int r = 0; r < 6; ++r) a += aL[h * 6 + r] * q_ro[r];
    Qg[((size_t)(b * H_ + h) * S_ + s) * D_ + d] = f2bf(a * qs);
  }
#pragma unroll
  for (int kv = 0; kv < 8; ++kv) {
    float ak = aL[96 + kv * 2] * k_ro[0] + aL[96 + kv * 2 + 1] * k_ro[1];
    Kg[((size_t)(b * KV_ + kv) * S_ + s) * D_ + d] = f2bf(ak * 0.5f);
    float av = aL[112 + kv * 2] * bv[0] + aL[112 + kv * 2 + 1] * bv[1];
    Vg[((size_t)(b * KV_ + kv) * S_ + s) * D_ + d] = f2bf(av * 0.5f);
  }
}

// ---------------- flash attention v3 (proven 148us): 256 thr, 1 head, KVB=32 ------
__global__ __launch_bounds__(256, 2)
void attn_kernel(const u16* __restrict__ Qg, const u16* __restrict__ Kg,
                 const u16* __restrict__ VTg, u16* __restrict__ Og) {
  __shared__ __align__(16) u16 Kbuf[2][8192];
  __shared__ __align__(16) u16 Vbuf[2][8192];
  __shared__ __align__(16) u16 Pbuf[4][512];

  const int t = threadIdx.x;
  const int lane = t & 63;
  const int lq = lane & 15, lg = lane >> 4;
  const int qw = t >> 6;
  const int h = blockIdx.x, b = blockIdx.y;
  const int qt = 31 - blockIdx.z;
  const int q0 = qt * 64;
  const int kvh = h >> 1;

  const u16* Kplane = Kg + (size_t)(b * KV_ + kvh) * S_ * D_;
  const u16* VTplane = VTg + (size_t)(b * KV_ + kvh) * D_ * S_;

  const int qg = q0 + qw * 16 + lq;
  const u16* Qrow = Qg + ((size_t)(b * H_ + h) * S_ + qg) * D_;
  short8 qf[8];
#pragma unroll
  for (int ks = 0; ks < 8; ++ks) qf[ks] = *(const short8*)(Qrow + ks * 32 + lg * 8);

  int ksrc[4], vsrc[4];
#pragma unroll
  for (int i = 0; i < 4; ++i) {
    const int kr = i * 8 + (t >> 5);
    ksrc[i] = kr * D_ + (((t & 31) ^ (kr & 7)) << 3);
    const int vr = i * 64 + (t >> 2);
    vsrc[i] = vr * S_ + (((t & 3) ^ ((vr >> 1) & 3)) << 3);
  }

  f32x4 zero = {0.f, 0.f, 0.f, 0.f};
  f32x4 oacc[16];
#pragma unroll
  for (int db = 0; db < 16; ++db) oacc[db] = zero;
  float m_s = NEG_, l_s = 0.f;

  const int qro = q0 + qw * 16 + lg * 4;
  const int nt = 2 * (qt + 1);

#pragma unroll
  for (int i = 0; i < 4; ++i) {
    gl_lds16(Kplane + ksrc[i], &Kbuf[0][0] + (i * 256 + t) * 8);
    gl_lds16(VTplane + vsrc[i], &Vbuf[0][0] + (i * 256 + t) * 8);
  }
  __syncthreads();
  int cur = 0;
  for (int it = 0; it < nt; ++it) {
    const int kv0 = it * 32;
    if (it + 1 < nt) {
      const u16* kp = Kplane + (size_t)(it + 1) * 32 * D_;
      const u16* vp = VTplane + (it + 1) * 32;
      u16* kd = &Kbuf[cur ^ 1][0];
      u16* vd = &Vbuf[cur ^ 1][0];
#pragma unroll
      for (int i = 0; i < 4; ++i) {
        gl_lds16(kp + ksrc[i], kd + (i * 256 + t) * 8);
        gl_lds16(vp + vsrc[i], vd + (i * 256 + t) * 8);
      }
    }
    const u16* Kb = &Kbuf[cur][0];
    f32x4 sacc[2];
    sacc[0] = zero; sacc[1] = zero;
    __builtin_amdgcn_s_setprio(1);
#pragma unroll
    for (int kb = 0; kb < 2; ++kb) {
      const int rbase = (kb * 16 + lq) * 256;
      const int sw = lq & 7;
#pragma unroll
      for (int ks = 0; ks < 8; ++ks) {
        short8 kf = *(const short8*)(Kb + rbase + (((ks * 4 + lg) ^ sw) << 3));
        sacc[kb] = __builtin_amdgcn_mfma_f32_16x16x32_bf16(kf, qf[ks], sacc[kb], 0, 0, 0);
      }
    }
    __builtin_amdgcn_s_setprio(0);
    const bool tail = (it >= 2 * qt);
#pragma unroll
    for (int kb = 0; kb < 2; ++kb)
#pragma unroll
      for (int r = 0; r < 4; ++r) {
        float x = sacc[kb][r];
        const float e = __expf(-fabsf(x) * 0.04f);
        const float th = (1.f - e) * __builtin_amdgcn_rcpf(1.f + e);
        x = copysignf(50.0f * th, x);
        if (tail && (kv0 + kb * 16 + lg * 4 + r > qg)) x = NEG_;
        sacc[kb][r] = x;
      }
    float vmax = fmaxf(fmaxf(fmaxf(sacc[0][0], sacc[0][1]), fmaxf(sacc[0][2], sacc[0][3])),
                       fmaxf(fmaxf(sacc[1][0], sacc[1][1]), fmaxf(sacc[1][2], sacc[1][3])));
    vmax = fmaxf(vmax, __shfl_xor(vmax, 16, 64));
    vmax = fmaxf(vmax, __shfl_xor(vmax, 32, 64));
    if (__any(vmax > m_s + 8.f)) {
      const float mn = fmaxf(m_s, vmax);
      const float c = __expf(m_s - mn);
      m_s = mn;
      l_s *= c;
      float c4[4];
#pragma unroll
      for (int r = 0; r < 4; ++r) c4[r] = __shfl(c, lg * 4 + r, 16);
#pragma unroll
      for (int db = 0; db < 16; ++db) {
        oacc[db][0] *= c4[0]; oacc[db][1] *= c4[1];
        oacc[db][2] *= c4[2]; oacc[db][3] *= c4[3];
      }
    }
    float ps = 0.f;
#pragma unroll
    for (int kb = 0; kb < 2; ++kb)
#pragma unroll
      for (int r = 0; r < 4; ++r) {
        const float p = __expf(sacc[kb][r] - m_s);
        sacc[kb][r] = p;
        ps += p;
      }
    ps += __shfl_xor(ps, 16, 64);
    ps += __shfl_xor(ps, 32, 64);
    l_s += ps;
    u16* Pw = &Pbuf[qw][0];
#pragma unroll
    for (int kb = 0; kb < 2; ++kb) {
      ushort4 pk;
      pk.x = f2bf(sacc[kb][0]); pk.y = f2bf(sacc[kb][1]);
      pk.z = f2bf(sacc[kb][2]); pk.w = f2bf(sacc[kb][3]);
      *(ushort4*)(Pw + 8 * lq + 128 * (2 * kb + (lg >> 1)) + 4 * (lg & 1)) = pk;
    }
    short8 pf = *(const short8*)(Pw + lane * 8);
    const u16* Vb = &Vbuf[cur][0];
    __builtin_amdgcn_s_setprio(1);
#pragma unroll
    for (int db = 0; db < 16; ++db) {
      const int d = db * 16 + lq;
      short8 vf = *(const short8*)(Vb + d * 32 + ((lg ^ ((lq >> 1) & 3)) << 3));
      oacc[db] = __builtin_amdgcn_mfma_f32_16x16x32_bf16(pf, vf, oacc[db], 0, 0, 0);
    }
    __builtin_amdgcn_s_setprio(0);
    __syncthreads();
    cur ^= 1;
  }
  const float invl = __builtin_amdgcn_rcpf(l_s);
  float inv4[4];
#pragma unroll
  for (int r = 0; r < 4; ++r) inv4[r] = __shfl(invl, lg * 4 + r, 16);
#pragma unroll
  for (int r = 0; r < 4; ++r) {
    u16* orow = Og + (size_t)(b * S_ + qro + r) * HD_ + h * D_;
#pragma unroll
    for (int db = 0; db < 16; ++db) orow[db * 16 + lq] = f2bf(oacc[db][r] * inv4[r]);
  }
}

// ---------------- launcher ----------------
extern "C" void kernel_launch(void* const* d_in, const int* in_sizes, int n_in,
                              void* d_out, int out_size, void* d_ws, size_t ws_size,
                              hipStream_t stream) {
  const float* hs    = (const float*)d_in[0];
  const float* freqs = (const float*)d_in[1];
  const float* W_A_q = (const float*)d_in[8];
  const float* W_A_k = (const float*)d_in[9];
  const float* W_A_v = (const float*)d_in[10];
  const float* W_B_q = (const float*)d_in[11];
  const float* W_B_k = (const float*)d_in[12];
  const float* W_B_v = (const float*)d_in[13];
  const float* Wo    = (const float*)d_in[14];
  const float* qw    = (const float*)d_in[15];
  const float* kw    = (const float*)d_in[16];
  float* out = (float*)d_out;

  char* ws = (char*)d_ws;
  u16* hsb = (u16*)(ws);                    // 4096x3584 bf16
  u16* WT  = (u16*)(ws + 29360128);         // 2688x3584 bf16
  u16* WoT = (u16*)(ws + 48627712);         // 3584x4096 bf16
  u16* Qg  = (u16*)(ws + 77987840);         // (B,H,S,D) bf16
  u16* Kg  = (u16*)(ws + 111542272);        // (B,KV,S,D) bf16
  u16* Vg  = (u16*)(ws + 128319488);        // (B,KV,S,D) bf16
  u16* VTg = (u16*)(ws + 145096704);        // (B,KV,D,S) bf16
  u16* AOg = (u16*)(ws + 161873920);        // (B*S, H*D) bf16
  u16* Pb  = (u16*)d_out;                   // 4096x2688 bf16 scratch inside d_out

  cvt_f32_bf16<<<1024, 256, 0, stream>>>(hs, hsb, MTOK * HID_);
  transpose_multi<<<dim3(112, 85), 256, 0, stream>>>(W_A_q, W_A_k, W_A_v, W_B_q, W_B_k, W_B_v, WT);
  transpose_f32_bf16<<<dim3(128, 112), 256, 0, stream>>>(Wo, WoT, HD_, HID_);

  gemm256<<<176, 512, 0, stream>>>(hsb, WT, Pb, NPROJ, HID_, HID_, NPROJ, 112, 11, 1);
  build_qkv<<<4096, 256, 0, stream>>>(Pb, freqs, qw, kw, Qg, Kg, Vg);
  transpose_bf16_v<<<dim3(32, 4, 16), 256, 0, stream>>>(Vg, VTg);
  attn_kernel<<<dim3(16, 2, 32), 256, 0, stream>>>(Qg, Kg, VTg, AOg);
  gemm256<<<224, 512, 0, stream>>>(AOg, WoT, out, HID_, HD_, HD_, HID_, 128, 14, 0);
}

// Round 15
// 401.845 us; speedup vs baseline: 1.2829x; 1.0315x over previous
//
#include <hip/hip_runtime.h>

// ---------------- problem constants ----------------
#define B_    2
#define S_    2048
#define HID_  3584
#define H_    16
#define KV_   8
#define D_    256
#define RQ_   6
#define NPROJ 2688
#define HD_   4096
#define MTOK  4096
#define EPS_  1e-6f
#define NEG_  -2.3819763e38f
#define SCALE_ 0.0625f   // 256^-0.5

typedef unsigned short u16;
typedef __attribute__((ext_vector_type(8))) short short8;
typedef __attribute__((ext_vector_type(4))) float f32x4;

__device__ __forceinline__ u16 f2bf(float f) {
  unsigned u = __float_as_uint(f);
  u += 0x7fffu + ((u >> 16) & 1u);
  return (u16)(u >> 16);
}

__device__ __forceinline__ float b2f(u16 b) {
  return __uint_as_float(((unsigned)b) << 16);
}

__device__ __forceinline__ void gl_lds16(const void* g, void* l) {
  __builtin_amdgcn_global_load_lds((__attribute__((address_space(1))) void*)g,
                                   (__attribute__((address_space(3))) void*)l, 16, 0, 0);
}

// ---------------- elementwise f32 -> bf16 ----------------
__global__ __launch_bounds__(256) void cvt_f32_bf16(const float* __restrict__ src,
                                                    u16* __restrict__ dst, int n) {
  int i = blockIdx.x * 256 + threadIdx.x;
  const int stride = gridDim.x * 256;
  const int n4 = n >> 2;
  for (; i < n4; i += stride) {
    float4 v = ((const float4*)src)[i];
    ushort4 o;
    o.x = f2bf(v.x); o.y = f2bf(v.y); o.z = f2bf(v.z); o.w = f2bf(v.w);
    ((ushort4*)dst)[i] = o;
  }
}

// ---------------- scalar transpose of the 3 small A-weight segments -> WT ---------
// segments: q:96@0, k:16@96, v:16@112; col-tiles 3,1,1 -> grid (112, 5)
__global__ __launch_bounds__(256) void transpose_multi(
    const float* __restrict__ s0, const float* __restrict__ s1,
    const float* __restrict__ s2, u16* __restrict__ WT) {
  const int y = blockIdx.y;
  const float* src; int cofs, C, c0;
  if      (y < 3)  { src = s0; cofs = 0;    C = 96;   c0 = y << 5; }
  else if (y < 4)  { src = s1; cofs = 96;   C = 16;   c0 = 0; }
  else             { src = s2; cofs = 112;  C = 16;   c0 = 0; }
  u16* dst = WT + (size_t)cofs * HID_;
  __shared__ float tile[32][33];
  const int tx = threadIdx.x & 31, ty = threadIdx.x >> 5;
  const int r0 = blockIdx.x << 5;
#pragma unroll
  for (int j = 0; j < 4; ++j) {
    int r = r0 + ty + j * 8, c = c0 + tx;
    tile[ty + j * 8][tx] = (c < C) ? src[(size_t)r * C + c] : 0.f;
  }
  __syncthreads();
#pragma unroll
  for (int j = 0; j < 4; ++j) {
    int cc = c0 + ty + j * 8, rr = r0 + tx;
    if (cc < C) dst[(size_t)cc * HID_ + rr] = f2bf(tile[tx][ty + j * 8]);
  }
}

// ---------------- vectorized 64x64 f32->bf16 transpose, merged segments -----------
// y<24: Bq(3584x1536)->WT+128*HID; y<32: Bk(3584x512)->WT+1664*HID;
// y<40: Bv(3584x512)->WT+2176*HID; y<96: Wo(4096x3584)->WoT.
// float4 loads + ushort4 stores (G13); LDS pad 69 -> <=2-way banks.
__global__ __launch_bounds__(256) void tr64_multi(
    const float* __restrict__ bq, const float* __restrict__ bk,
    const float* __restrict__ bv, const float* __restrict__ wo,
    u16* __restrict__ WT, u16* __restrict__ WoT) {
  const int y = blockIdx.y;
  const float* src; u16* dst; int C, R, c0;
  if      (y < 24) { src = bq; dst = WT + (size_t)128 * HID_;  C = 1536; R = HID_; c0 = y << 6; }
  else if (y < 32) { src = bk; dst = WT + (size_t)1664 * HID_; C = 512;  R = HID_; c0 = (y - 24) << 6; }
  else if (y < 40) { src = bv; dst = WT + (size_t)2176 * HID_; C = 512;  R = HID_; c0 = (y - 32) << 6; }
  else             { src = wo; dst = WoT;                      C = HID_; R = HD_;  c0 = (y - 40) << 6; }
  const int r0 = blockIdx.x << 6;
  if (r0 >= R) return;
  __shared__ float tile[64][69];
  const int t = threadIdx.x;
  const int rg = t >> 4, cx = (t & 15) << 2;
#pragma unroll
  for (int j = 0; j < 4; ++j) {
    const int row = rg + j * 16;
    const float4 v = *(const float4*)(src + (size_t)(r0 + row) * C + c0 + cx);
    tile[row][cx + 0] = v.x; tile[row][cx + 1] = v.y;
    tile[row][cx + 2] = v.z; tile[row][cx + 3] = v.w;
  }
  __syncthreads();
#pragma unroll
  for (int j = 0; j < 4; ++j) {
    const int crow = rg + j * 16;
    ushort4 o;
    o.x = f2bf(tile[cx + 0][crow]); o.y = f2bf(tile[cx + 1][crow]);
    o.z = f2bf(tile[cx + 2][crow]); o.w = f2bf(tile[cx + 3][crow]);
    *(ushort4*)(dst + (size_t)(c0 + crow) * R + r0 + cx) = o;
  }
}

// ---------------- vectorized bf16 transpose: (S_ x D_) -> (D_ x S_), batched z -----
__global__ __launch_bounds__(256) void transpose_bf16_v(const u16* __restrict__ src,
                                                        u16* __restrict__ dst) {
  __shared__ u16 tile[64][70];
  const size_t plane = (size_t)S_ * D_;
  const u16* s = src + (size_t)blockIdx.z * plane;
  u16* d = dst + (size_t)blockIdx.z * plane;
  const int t = threadIdx.x;
  const int r0 = blockIdx.x << 6;
  const int c0 = blockIdx.y << 6;
  const int cx = (t & 15) << 2;
  const int rg = t >> 4;
#pragma unroll
  for (int jj = 0; jj < 4; ++jj) {
    const int row = rg + jj * 16;
    const ushort4 v = *(const ushort4*)(s + (size_t)(r0 + row) * D_ + c0 + cx);
    tile[row][cx + 0] = v.x; tile[row][cx + 1] = v.y;
    tile[row][cx + 2] = v.z; tile[row][cx + 3] = v.w;
  }
  __syncthreads();
#pragma unroll
  for (int jj = 0; jj < 4; ++jj) {
    const int crow = rg + jj * 16;
    ushort4 o;
    o.x = tile[cx + 0][crow]; o.y = tile[cx + 1][crow];
    o.z = tile[cx + 2][crow]; o.w = tile[cx + 3][crow];
    *(ushort4*)(d + (size_t)(c0 + crow) * S_ + r0 + cx) = o;
  }
}

// ---------------- 256x256 GEMM, BK=32, 4-slot LDS ring, deep counted-vmcnt --------
__global__ __launch_bounds__(512, 1)
void gemm256(const u16* __restrict__ A, const u16* __restrict__ Bm, void* __restrict__ Cv,
             int N, int lda, int ldb, int ldc, int NT, int GY, int obf) {
  __shared__ __align__(16) u16 ring[4][2][8192];
  const int t = threadIdx.x;
  const int lane = t & 63;
  const int lq = lane & 15, lg = lane >> 4;
  const int w = t >> 6;
  const int wm = w >> 2, wn = w & 3;

  const int wg = blockIdx.x;
  const int chunk = gridDim.x >> 3;
  const int gid = (wg & 7) * chunk + (wg >> 3);
  const int bm0 = (gid / GY) * 256, bn0 = (gid % GY) * 256;

  const int rsub = lane >> 2;
  const int ksub = (((lane & 3) ^ ((lane >> 3) & 3)) << 3);
  const u16* paw = A + (size_t)(bm0 + w * 32 + rsub) * lda + ksub;
  const u16* pbw = Bm + (size_t)(bn0 + w * 32 + rsub) * ldb + ksub;

  const int rdo = lq * 32 + ((lg ^ ((lq >> 1) & 3)) << 3);

  f32x4 zero = {0.f, 0.f, 0.f, 0.f};
  f32x4 acc[8][4];
#pragma unroll
  for (int m = 0; m < 8; ++m)
#pragma unroll
    for (int n = 0; n < 4; ++n) acc[m][n] = zero;

#define STAGE_(T)                                                              \
  {                                                                            \
    const int slot_ = (T) & 3;                                                 \
    const size_t ko_ = (size_t)(T) * 32;                                       \
    gl_lds16(paw + ko_,            &ring[slot_][0][(2 * w + 0) * 512]);        \
    gl_lds16(paw + 16 * lda + ko_, &ring[slot_][0][(2 * w + 1) * 512]);        \
    gl_lds16(pbw + ko_,            &ring[slot_][1][(2 * w + 0) * 512]);        \
    gl_lds16(pbw + 16 * ldb + ko_, &ring[slot_][1][(2 * w + 1) * 512]);        \
  }

  STAGE_(0);
  STAGE_(1);
  STAGE_(2);
  asm volatile("s_waitcnt vmcnt(8)" ::: "memory");
  __builtin_amdgcn_s_barrier();

  for (int T = 0; T < NT; ++T) {
    __builtin_amdgcn_sched_barrier(0);
    const int s = T & 3;
    const u16* as = &ring[s][0][wm * 4096];
    const u16* bs = &ring[s][1][wn * 2048];
    short8 af[8], bf[4];
#pragma unroll
    for (int m = 0; m < 8; ++m) af[m] = *(const short8*)(as + m * 512 + rdo);
#pragma unroll
    for (int n = 0; n < 4; ++n) bf[n] = *(const short8*)(bs + n * 512 + rdo);
    if (T + 3 < NT) STAGE_(T + 3);
    __builtin_amdgcn_s_setprio(1);
#pragma unroll
    for (int m = 0; m < 8; ++m)
#pragma unroll
      for (int n = 0; n < 4; ++n)
        acc[m][n] = __builtin_amdgcn_mfma_f32_16x16x32_bf16(af[m], bf[n], acc[m][n], 0, 0, 0);
    __builtin_amdgcn_s_setprio(0);
    if (T + 3 < NT)      { asm volatile("s_waitcnt vmcnt(8) lgkmcnt(0)" ::: "memory"); }
    else if (T + 2 < NT) { asm volatile("s_waitcnt vmcnt(4) lgkmcnt(0)" ::: "memory"); }
    else if (T + 1 < NT) { asm volatile("s_waitcnt vmcnt(0) lgkmcnt(0)" ::: "memory"); }
    else                 { asm volatile("s_waitcnt lgkmcnt(0)" ::: "memory"); }
    __builtin_amdgcn_s_barrier();
  }
#undef STAGE_

#pragma unroll
  for (int m = 0; m < 8; ++m) {
    const int row = bm0 + wm * 128 + m * 16 + lg * 4;
#pragma unroll
    for (int n = 0; n < 4; ++n) {
      const int col = bn0 + wn * 64 + n * 16 + lq;
      if (col < N) {
        if (obf) {
          u16* cp = (u16*)Cv + (size_t)row * ldc + col;
          cp[0] = f2bf(acc[m][n][0]);
          cp[(size_t)ldc] = f2bf(acc[m][n][1]);
          cp[(size_t)2 * ldc] = f2bf(acc[m][n][2]);
          cp[(size_t)3 * ldc] = f2bf(acc[m][n][3]);
        } else {
          float* cp = (float*)Cv + (size_t)row * ldc + col;
          cp[0] = acc[m][n][0];
          cp[(size_t)ldc] = acc[m][n][1];
          cp[(size_t)2 * ldc] = acc[m][n][2];
          cp[(size_t)3 * ldc] = acc[m][n][3];
        }
      }
    }
  }
}

// ---------------- per-token RMSNorm + RoPE + rank contraction -> Q,K,V (bf16) ------
__global__ __launch_bounds__(256)
void build_qkv(const u16* __restrict__ P, const float* __restrict__ freqs,
               const float* __restrict__ qw, const float* __restrict__ kw,
               u16* __restrict__ Qg, u16* __restrict__ Kg, u16* __restrict__ Vg) {
  const int token = blockIdx.x;
  const int b = token >> 11, s = token & 2047;
  const int d = threadIdx.x;
  const u16* row = P + (size_t)token * NPROJ;
  __shared__ float aL[128];
  __shared__ float rQ[6][256];
  __shared__ float rK[2][256];
  __shared__ float red[4][8];

  if (d < 128) aL[d] = b2f(row[d]);
  float bq[6], bk[2], bv[2];
#pragma unroll
  for (int r = 0; r < 6; ++r) bq[r] = b2f(row[128 + r * 256 + d]);
#pragma unroll
  for (int r = 0; r < 2; ++r) bk[r] = b2f(row[1664 + r * 256 + d]);
#pragma unroll
  for (int r = 0; r < 2; ++r) bv[r] = b2f(row[2176 + r * 256 + d]);

  float sq[8];
#pragma unroll
  for (int r = 0; r < 6; ++r) sq[r] = bq[r] * bq[r];
  sq[6] = bk[0] * bk[0];
  sq[7] = bk[1] * bk[1];
#pragma unroll
  for (int j = 0; j < 8; ++j) {
    sq[j] += __shfl_xor(sq[j], 32, 64);
    sq[j] += __shfl_xor(sq[j], 16, 64);
    sq[j] += __shfl_xor(sq[j], 8, 64);
    sq[j] += __shfl_xor(sq[j], 4, 64);
    sq[j] += __shfl_xor(sq[j], 2, 64);
    sq[j] += __shfl_xor(sq[j], 1, 64);
  }
  const int lane = d & 63, wv = d >> 6;
  if (lane == 0) {
#pragma unroll
    for (int j = 0; j < 8; ++j) red[wv][j] = sq[j];
  }
  __syncthreads();
  float inv[8];
#pragma unroll
  for (int j = 0; j < 8; ++j) {
    float ss = red[0][j] + red[1][j] + red[2][j] + red[3][j];
    inv[j] = rsqrtf(ss * (1.0f / 256.0f) + EPS_);
  }
  const float gq = 1.f + qw[d], gk = 1.f + kw[d];
#pragma unroll
  for (int r = 0; r < 6; ++r) rQ[r][d] = bq[r] * inv[r] * gq;
#pragma unroll
  for (int r = 0; r < 2; ++r) rK[r][d] = bk[r] * inv[6 + r] * gk;
  __syncthreads();

  const int dh = d & 127;
  const float co = freqs[(s * 128 + dh) * 2 + 0];
  const float sn = freqs[(s * 128 + dh) * 2 + 1];
  float q_ro[6], k_ro[2];
  if (d < 128) {
#pragma unroll
    for (int r = 0; r < 6; ++r) q_ro[r] = rQ[r][d] * co - rQ[r][d + 128] * sn;
#pragma unroll
    for (int r = 0; r < 2; ++r) k_ro[r] = rK[r][d] * co - rK[r][d + 128] * sn;
  } else {
#pragma unroll
    for (int r = 0; r < 6; ++r) q_ro[r] = rQ[r][d] * co + rQ[r][d - 128] * sn;
#pragma unroll
    for (int r = 0; r < 2; ++r) k_ro[r] = rK[r][d] * co + rK[r][d - 128] * sn;
  }
  const float qs = SCALE_ * (1.0f / 6.0f);
#pragma unroll
  for (int h = 0; h < 16; ++h) {
    float a = 0.f;
#pragma unroll
    for (int r = 0; r < 6; ++r) a += aL[h * 6 + r] * q_ro[r];
    Qg[((size_t)(b * H_ + h) * S_ + s) * D_ + d] = f2bf(a * qs);
  }
#pragma unroll
  for (int kv = 0; kv < 8; ++kv) {
    float ak = aL[96 + kv * 2] * k_ro[0] + aL[96 + kv * 2 + 1] * k_ro[1];
    Kg[((size_t)(b * KV_ + kv) * S_ + s) * D_ + d] = f2bf(ak * 0.5f);
    float av = aL[112 + kv * 2] * bv[0] + aL[112 + kv * 2 + 1] * bv[1];
    Vg[((size_t)(b * KV_ + kv) * S_ + s) * D_ + d] = f2bf(av * 0.5f);
  }
}

// ---------------- flash attention v3 (proven 148us): 256 thr, 1 head, KVB=32 ------
__global__ __launch_bounds__(256, 2)
void attn_kernel(const u16* __restrict__ Qg, const u16* __restrict__ Kg,
                 const u16* __restrict__ VTg, u16* __restrict__ Og) {
  __shared__ __align__(16) u16 Kbuf[2][8192];
  __shared__ __align__(16) u16 Vbuf[2][8192];
  __shared__ __align__(16) u16 Pbuf[4][512];

  const int t = threadIdx.x;
  const int lane = t & 63;
  const int lq = lane & 15, lg = lane >> 4;
  const int qw = t >> 6;
  const int h = blockIdx.x, b = blockIdx.y;
  const int qt = 31 - blockIdx.z;
  const int q0 = qt * 64;
  const int kvh = h >> 1;

  const u16* Kplane = Kg + (size_t)(b * KV_ + kvh) * S_ * D_;
  const u16* VTplane = VTg + (size_t)(b * KV_ + kvh) * D_ * S_;

  const int qg = q0 + qw * 16 + lq;
  const u16* Qrow = Qg + ((size_t)(b * H_ + h) * S_ + qg) * D_;
  short8 qf[8];
#pragma unroll
  for (int ks = 0; ks < 8; ++ks) qf[ks] = *(const short8*)(Qrow + ks * 32 + lg * 8);

  int ksrc[4], vsrc[4];
#pragma unroll
  for (int i = 0; i < 4; ++i) {
    const int kr = i * 8 + (t >> 5);
    ksrc[i] = kr * D_ + (((t & 31) ^ (kr & 7)) << 3);
    const int vr = i * 64 + (t >> 2);
    vsrc[i] = vr * S_ + (((t & 3) ^ ((vr >> 1) & 3)) << 3);
  }

  f32x4 zero = {0.f, 0.f, 0.f, 0.f};
  f32x4 oacc[16];
#pragma unroll
  for (int db = 0; db < 16; ++db) oacc[db] = zero;
  float m_s = NEG_, l_s = 0.f;

  const int qro = q0 + qw * 16 + lg * 4;
  const int nt = 2 * (qt + 1);

#pragma unroll
  for (int i = 0; i < 4; ++i) {
    gl_lds16(Kplane + ksrc[i], &Kbuf[0][0] + (i * 256 + t) * 8);
    gl_lds16(VTplane + vsrc[i], &Vbuf[0][0] + (i * 256 + t) * 8);
  }
  __syncthreads();
  int cur = 0;
  for (int it = 0; it < nt; ++it) {
    const int kv0 = it * 32;
    if (it + 1 < nt) {
      const u16* kp = Kplane + (size_t)(it + 1) * 32 * D_;
      const u16* vp = VTplane + (it + 1) * 32;
      u16* kd = &Kbuf[cur ^ 1][0];
      u16* vd = &Vbuf[cur ^ 1][0];
#pragma unroll
      for (int i = 0; i < 4; ++i) {
        gl_lds16(kp + ksrc[i], kd + (i * 256 + t) * 8);
        gl_lds16(vp + vsrc[i], vd + (i * 256 + t) * 8);
      }
    }
    const u16* Kb = &Kbuf[cur][0];
    f32x4 sacc[2];
    sacc[0] = zero; sacc[1] = zero;
    __builtin_amdgcn_s_setprio(1);
#pragma unroll
    for (int kb = 0; kb < 2; ++kb) {
      const int rbase = (kb * 16 + lq) * 256;
      const int sw = lq & 7;
#pragma unroll
      for (int ks = 0; ks < 8; ++ks) {
        short8 kf = *(const short8*)(Kb + rbase + (((ks * 4 + lg) ^ sw) << 3));
        sacc[kb] = __builtin_amdgcn_mfma_f32_16x16x32_bf16(kf, qf[ks], sacc[kb], 0, 0, 0);
      }
    }
    __builtin_amdgcn_s_setprio(0);
    const bool tail = (it >= 2 * qt);
#pragma unroll
    for (int kb = 0; kb < 2; ++kb)
#pragma unroll
      for (int r = 0; r < 4; ++r) {
        float x = sacc[kb][r];
        const float e = __expf(-fabsf(x) * 0.04f);
        const float th = (1.f - e) * __builtin_amdgcn_rcpf(1.f + e);
        x = copysignf(50.0f * th, x);
        if (tail && (kv0 + kb * 16 + lg * 4 + r > qg)) x = NEG_;
        sacc[kb][r] = x;
      }
    float vmax = fmaxf(fmaxf(fmaxf(sacc[0][0], sacc[0][1]), fmaxf(sacc[0][2], sacc[0][3])),
                       fmaxf(fmaxf(sacc[1][0], sacc[1][1]), fmaxf(sacc[1][2], sacc[1][3])));
    vmax = fmaxf(vmax, __shfl_xor(vmax, 16, 64));
    vmax = fmaxf(vmax, __shfl_xor(vmax, 32, 64));
    if (__any(vmax > m_s + 8.f)) {
      const float mn = fmaxf(m_s, vmax);
      const float c = __expf(m_s - mn);
      m_s = mn;
      l_s *= c;
      float c4[4];
#pragma unroll
      for (int r = 0; r < 4; ++r) c4[r] = __shfl(c, lg * 4 + r, 16);
#pragma unroll
      for (int db = 0; db < 16; ++db) {
        oacc[db][0] *= c4[0]; oacc[db][1] *= c4[1];
        oacc[db][2] *= c4[2]; oacc[db][3] *= c4[3];
      }
    }
    float ps = 0.f;
#pragma unroll
    for (int kb = 0; kb < 2; ++kb)
#pragma unroll
      for (int r = 0; r < 4; ++r) {
        const float p = __expf(sacc[kb][r] - m_s);
        sacc[kb][r] = p;
        ps += p;
      }
    ps += __shfl_xor(ps, 16, 64);
    ps += __shfl_xor(ps, 32, 64);
    l_s += ps;
    u16* Pw = &Pbuf[qw][0];
#pragma unroll
    for (int kb = 0; kb < 2; ++kb) {
      ushort4 pk;
      pk.x = f2bf(sacc[kb][0]); pk.y = f2bf(sacc[kb][1]);
      pk.z = f2bf(sacc[kb][2]); pk.w = f2bf(sacc[kb][3]);
      *(ushort4*)(Pw + 8 * lq + 128 * (2 * kb + (lg >> 1)) + 4 * (lg & 1)) = pk;
    }
    short8 pf = *(const short8*)(Pw + lane * 8);
    const u16* Vb = &Vbuf[cur][0];
    __builtin_amdgcn_s_setprio(1);
#pragma unroll
    for (int db = 0; db < 16; ++db) {
      const int d = db * 16 + lq;
      short8 vf = *(const short8*)(Vb + d * 32 + ((lg ^ ((lq >> 1) & 3)) << 3));
      oacc[db] = __builtin_amdgcn_mfma_f32_16x16x32_bf16(pf, vf, oacc[db], 0, 0, 0);
    }
    __builtin_amdgcn_s_setprio(0);
    __syncthreads();
    cur ^= 1;
  }
  const float invl = __builtin_amdgcn_rcpf(l_s);
  float inv4[4];
#pragma unroll
  for (int r = 0; r < 4; ++r) inv4[r] = __shfl(invl, lg * 4 + r, 16);
#pragma unroll
  for (int r = 0; r < 4; ++r) {
    u16* orow = Og + (size_t)(b * S_ + qro + r) * HD_ + h * D_;
#pragma unroll
    for (int db = 0; db < 16; ++db) orow[db * 16 + lq] = f2bf(oacc[db][r] * inv4[r]);
  }
}

// ---------------- launcher ----------------
extern "C" void kernel_launch(void* const* d_in, const int* in_sizes, int n_in,
                              void* d_out, int out_size, void* d_ws, size_t ws_size,
                              hipStream_t stream) {
  const float* hs    = (const float*)d_in[0];
  const float* freqs = (const float*)d_in[1];
  const float* W_A_q = (const float*)d_in[8];
  const float* W_A_k = (const float*)d_in[9];
  const float* W_A_v = (const float*)d_in[10];
  const float* W_B_q = (const float*)d_in[11];
  const float* W_B_k = (const float*)d_in[12];
  const float* W_B_v = (const float*)d_in[13];
  const float* Wo    = (const float*)d_in[14];
  const float* qw    = (const float*)d_in[15];
  const float* kw    = (const float*)d_in[16];
  float* out = (float*)d_out;

  char* ws = (char*)d_ws;
  u16* hsb = (u16*)(ws);                    // 4096x3584 bf16
  u16* WT  = (u16*)(ws + 29360128);         // 2688x3584 bf16
  u16* WoT = (u16*)(ws + 48627712);         // 3584x4096 bf16
  u16* Qg  = (u16*)(ws + 77987840);         // (B,H,S,D) bf16
  u16* Kg  = (u16*)(ws + 111542272);        // (B,KV,S,D) bf16
  u16* Vg  = (u16*)(ws + 128319488);        // (B,KV,S,D) bf16
  u16* VTg = (u16*)(ws + 145096704);        // (B,KV,D,S) bf16
  u16* AOg = (u16*)(ws + 161873920);        // (B*S, H*D) bf16
  u16* Pb  = (u16*)d_out;                   // 4096x2688 bf16 scratch inside d_out

  cvt_f32_bf16<<<1024, 256, 0, stream>>>(hs, hsb, MTOK * HID_);
  transpose_multi<<<dim3(112, 5), 256, 0, stream>>>(W_A_q, W_A_k, W_A_v, WT);
  tr64_multi<<<dim3(64, 96), 256, 0, stream>>>(W_B_q, W_B_k, W_B_v, Wo, WT, WoT);

  gemm256<<<176, 512, 0, stream>>>(hsb, WT, Pb, NPROJ, HID_, HID_, NPROJ, 112, 11, 1);
  build_qkv<<<4096, 256, 0, stream>>>(Pb, freqs, qw, kw, Qg, Kg, Vg);
  transpose_bf16_v<<<dim3(32, 4, 16), 256, 0, stream>>>(Vg, VTg);
  attn_kernel<<<dim3(16, 2, 32), 256, 0, stream>>>(Qg, Kg, VTg, AOg);
  gemm256<<<224, 512, 0, stream>>>(AOg, WoT, out, HID_, HD_, HD_, HID_, 128, 14, 0);
}